// Round 3
// baseline (1048.437 us; speedup 1.0000x reference)
//
#include <hip/hip_runtime.h>
#include <cstdint>
#include <cmath>

#define NB 256      // graphs (B)
#define MM 256      // nodes per graph
#define NN (NB*MM)  // 65536 nodes
#define KNN 15
#define FIN 7
#define CC 128
#define C2 768
#define NL 3
#define FINF 3.4e38f

__device__ __forceinline__ float lrelu(float v){ return v > 0.f ? v : 0.01f*v; }

// ---------------------------------------------------------------- kNN -------
// Wave-per-node, u64-packed keys: key = (f32bits(d2) << 32) | idx. d2 >= 0
// (clamped) so u32 ordering == f32 ordering; idx in the low bits gives the
// reference's lowest-index tie-break for free. Butterfly step = 2 swizzle +
// 1 cmp_u64 + 2 cndmask (vs ~9 instrs for the float+idx compound compare).
__global__ __launch_bounds__(256) void knn_kernel(const float* __restrict__ x,
                                                  int* __restrict__ knn){
  __shared__ float4 pos[MM];
  __shared__ float  sq[MM];
  const int g = blockIdx.x >> 6;               // 64 blocks per graph
  const int t = threadIdx.x;
  const float* xr = x + (size_t)(g*MM + t)*FIN;
  float4 p = make_float4(xr[0], xr[1], xr[2], xr[3]);
  pos[t] = p;
  sq[t]  = p.x*p.x + p.y*p.y + p.z*p.z + p.w*p.w;
  __syncthreads();

  const int i    = (blockIdx.x & 63)*4 + (t >> 6);  // local node this wave owns
  const int lane = t & 63;
  const float4 pi = pos[i];
  const float  sqi = sq[i];

  unsigned long long k[4];
#pragma unroll
  for (int q=0;q<4;q++){
    int j = q*64 + lane;
    float4 pj = pos[j];
    float dot = pi.x*pj.x + pi.y*pj.y + pi.z*pj.z + pi.w*pj.w;
    float d2 = fmaxf(sqi + sq[j] - 2.f*dot, 0.f);
    k[q] = ((unsigned long long)__float_as_uint(d2) << 32) | (unsigned)j;
    if (j == i) k[q] = ~0ull;                 // self-exclusion
  }

  int keep = 0;
#pragma unroll
  for (int it=0; it<KNN; it++){
    unsigned long long m01 = k[0] < k[1] ? k[0] : k[1];
    unsigned long long m23 = k[2] < k[3] ? k[2] : k[3];
    unsigned long long b   = m01  < m23  ? m01  : m23;
#pragma unroll
    for (int off=1; off<64; off<<=1){
      unsigned long long o = __shfl_xor(b, off);
      b = o < b ? o : b;
    }
    if (lane == it) keep = (int)(unsigned)b;  // low 32 bits = local idx j
    // consume the unique winner
#pragma unroll
    for (int q=0;q<4;q++) if (k[q] == b) k[q] = ~0ull;
  }
  if (lane < KNN)
    knn[(size_t)(g*MM + i)*KNN + lane] = g*MM + keep;
}

// ------------------------------------------------------------ aggregation ---
// norm is constant 1/15 (every node is dst exactly 15 times -> deg==15).
__global__ void agg7_kernel(const float* __restrict__ src,
                            const int* __restrict__ knn,
                            float* __restrict__ out){
  int i = blockIdx.x*blockDim.x + threadIdx.x;
  if (i >= NN*FIN) return;
  int n = i / FIN, c = i - n*FIN;
  const int* kn = knn + (size_t)n*KNN;
  float s = 0.f;
#pragma unroll
  for (int k=0;k<KNN;k++) s += src[(size_t)kn[k]*FIN + c];
  out[i] = s * (1.f/15.f);
}

__global__ __launch_bounds__(128) void agg128_kernel(const float* __restrict__ src,
                                                     const int* __restrict__ knn,
                                                     float* __restrict__ out){
  const int tid = threadIdx.x;
  const int n   = blockIdx.x*4 + (tid >> 5);
  const int c4  = (tid & 31) * 4;
  const int* kn = knn + (size_t)n*KNN;
  float4 s = make_float4(0.f,0.f,0.f,0.f);
#pragma unroll
  for (int k=0;k<KNN;k++){
    float4 v = *(const float4*)(src + (size_t)kn[k]*CC + c4);
    s.x += v.x; s.y += v.y; s.z += v.z; s.w += v.w;
  }
  float4 o = make_float4(s.x*(1.f/15.f), s.y*(1.f/15.f),
                         s.z*(1.f/15.f), s.w*(1.f/15.f));
  *(float4*)(out + (size_t)n*CC + c4) = o;
}

// ------------------------------------------------------------ conv layer 1 --
__global__ __launch_bounds__(128) void conv1_kernel(const float* __restrict__ x,
                                                    const float* __restrict__ a1,
                                                    const float* __restrict__ a2,
                                                    const float* __restrict__ W,
                                                    const float* __restrict__ b,
                                                    float* __restrict__ out){
  __shared__ float s[3*FIN];
  const int n = blockIdx.x, c = threadIdx.x;
  if (c < FIN)        s[c] = x [(size_t)n*FIN + c];
  else if (c < 2*FIN) s[c] = a1[(size_t)n*FIN + (c-FIN)];
  else if (c < 3*FIN) s[c] = a2[(size_t)n*FIN + (c-2*FIN)];
  __syncthreads();
  float acc = b[c];
#pragma unroll
  for (int t=0;t<3*FIN;t++) acc += s[t] * W[t*CC + c];
  out[(size_t)n*CC + c] = lrelu(acc);
}

// -------------------------------------------------- conv layers 2/3 (GEMM) --
#define CMT 64
__global__ __launch_bounds__(256) void conv_gemm_kernel(const float* __restrict__ p0,
                                                        const float* __restrict__ p1,
                                                        const float* __restrict__ p2,
                                                        const float* __restrict__ W,
                                                        const float* __restrict__ b,
                                                        float* __restrict__ out){
  __shared__ float Ast[32][CMT];   // [kk][r]
  __shared__ float Ws [32][CC];    // [kk][c]
  const int tid = threadIdx.x;
  const int row0 = blockIdx.x * CMT;
  const int tr = tid >> 5, tc = tid & 31;
  float acc[8][4];
#pragma unroll
  for (int i=0;i<8;i++)
#pragma unroll
    for (int j=0;j<4;j++) acc[i][j]=0.f;

#pragma unroll
  for (int hop=0; hop<3; hop++){
    const float* A  = (hop==0 ? p0 : hop==1 ? p1 : p2) + (size_t)row0*CC;
    const float* Wh = W + (size_t)hop*CC*CC;
    for (int kt=0; kt<4; kt++){
      __syncthreads();
#pragma unroll
      for (int q=0;q<2;q++){
        int chunk = tid + q*256;
        int r   = chunk >> 3;
        int kc4 = (chunk & 7) * 4;
        float4 v = *(const float4*)(A + (size_t)r*CC + kt*32 + kc4);
        Ast[kc4+0][r] = v.x; Ast[kc4+1][r] = v.y;
        Ast[kc4+2][r] = v.z; Ast[kc4+3][r] = v.w;
      }
#pragma unroll
      for (int q=0;q<4;q++){
        int chunk = tid + q*256;
        int kr = chunk >> 5;
        int c4 = (chunk & 31) * 4;
        *(float4*)(&Ws[kr][c4]) = *(const float4*)(Wh + (size_t)(kt*32+kr)*CC + c4);
      }
      __syncthreads();
#pragma unroll 8
      for (int kk=0;kk<32;kk++){
        float4 w  = *(const float4*)(&Ws[kk][tc*4]);
        float4 a0 = *(const float4*)(&Ast[kk][tr*8]);
        float4 a1 = *(const float4*)(&Ast[kk][tr*8+4]);
        float av[8] = {a0.x,a0.y,a0.z,a0.w,a1.x,a1.y,a1.z,a1.w};
        float wv[4] = {w.x,w.y,w.z,w.w};
#pragma unroll
        for (int i=0;i<8;i++)
#pragma unroll
          for (int j=0;j<4;j++) acc[i][j] += av[i]*wv[j];
      }
    }
  }
  const int c0 = tc*4;
  float4 bv = *(const float4*)(b + c0);
  float bb[4] = {bv.x,bv.y,bv.z,bv.w};
#pragma unroll
  for (int i=0;i<8;i++){
    int r = row0 + tr*8 + i;
    float4 o;
    o.x = lrelu(acc[i][0]+bb[0]);
    o.y = lrelu(acc[i][1]+bb[1]);
    o.z = lrelu(acc[i][2]+bb[2]);
    o.w = lrelu(acc[i][3]+bb[3]);
    *(float4*)(out + (size_t)r*CC + c0) = o;
  }
}

// ------------------------------------------------------------------ pooling -
__global__ __launch_bounds__(512) void pool_kernel(const float* __restrict__ h,
                                                   float* __restrict__ gf, int off){
  __shared__ float smean[4][CC];
  __shared__ float smax [4][CC];
  const int g = blockIdx.x, tid = threadIdx.x;
  const int c = tid & 127, grp = tid >> 7;
  const float* hp = h + (size_t)g*MM*CC + c;
  float s = 0.f, mx = -FINF;
  for (int m=grp*64; m<grp*64+64; m++){
    float v = hp[(size_t)m*CC];
    s += v; mx = fmaxf(mx, v);
  }
  smean[grp][c] = s; smax[grp][c] = mx;
  __syncthreads();
  if (grp == 0){
    s  = smean[0][c] + smean[1][c] + smean[2][c] + smean[3][c];
    mx = fmaxf(fmaxf(smax[0][c], smax[1][c]), fmaxf(smax[2][c], smax[3][c]));
    gf[(size_t)g*C2 + off + c]      = s * (1.f/MM);
    gf[(size_t)g*C2 + off + CC + c] = mx;
  }
}

// ---------------------------------------------------------------- batchnorm -
// 12 blocks x 64 channels; 4 row-groups of 64 rows each; LDS combine.
__global__ __launch_bounds__(256) void bn_kernel(float* __restrict__ g,
                                                 const float* __restrict__ gamma,
                                                 const float* __restrict__ beta){
  __shared__ float ssum[4][64], ssq[4][64], ssc[64], ssh[64];
  const int cl = threadIdx.x & 63, rg = threadIdx.x >> 6;
  const int c  = blockIdx.x*64 + cl;
  float s=0.f, q=0.f;
  for (int r=rg*64; r<rg*64+64; r++){
    float v = g[(size_t)r*C2 + c];
    s += v; q += v*v;
  }
  ssum[rg][cl]=s; ssq[rg][cl]=q;
  __syncthreads();
  if (rg == 0){
    s = ssum[0][cl]+ssum[1][cl]+ssum[2][cl]+ssum[3][cl];
    q = ssq [0][cl]+ssq [1][cl]+ssq [2][cl]+ssq [3][cl];
    float mu  = s * (1.f/NB);
    float var = q * (1.f/NB) - mu*mu;
    float sc  = rsqrtf(var + 1e-5f) * gamma[c];
    ssc[cl] = sc;
    ssh[cl] = beta[c] - mu*sc;
  }
  __syncthreads();
  const float sc = ssc[cl], sh = ssh[cl];
  for (int r=rg*64; r<rg*64+64; r++){
    size_t ix = (size_t)r*C2 + c;
    g[ix] = g[ix]*sc + sh;
  }
}

// ------------------------------------------- fused MLP (5 layers + head) ----
// 64 blocks x 768 threads; block owns 4 rows. Row state ping-pongs in LDS.
// Thread = (row r = t/192, col-quad c4 = (t%192)*4); every wave is uniform
// in r (192 = 3 waves). W read straight from L2 as coalesced float4.
__global__ __launch_bounds__(768) void mlp_fused_kernel(
    const float* __restrict__ g,
    const float* __restrict__ W1, const float* __restrict__ b1,
    const float* __restrict__ W2, const float* __restrict__ b2,
    const float* __restrict__ W3, const float* __restrict__ b3,
    const float* __restrict__ W4, const float* __restrict__ b4,
    const float* __restrict__ W5, const float* __restrict__ b5,
    const float* __restrict__ Wo, const float* __restrict__ bo,
    float* __restrict__ out){
  __shared__ float buf[2][4][C2];
  const int tid = threadIdx.x;
  const int r   = tid / 192;
  const int c4  = (tid - r*192) * 4;
  const int row = blockIdx.x*4 + r;

  *(float4*)(&buf[0][r][c4]) = *(const float4*)(g + (size_t)row*C2 + c4);
  __syncthreads();

  const float* Ws[5] = {W1,W2,W3,W4,W5};
  const float* bs[5] = {b1,b2,b3,b4,b5};
  int cb = 0;
  for (int l=0; l<5; l++){
    const float* W = Ws[l];
    const float (*cur)[C2] = buf[cb];
    float4 acc = *(const float4*)(bs[l] + c4);
    for (int k=0; k<C2; k+=4){
      float4 av = *(const float4*)(&cur[r][k]);
      const float* Wr = W + (size_t)k*C2 + c4;
      float4 w0 = *(const float4*)(Wr);
      float4 w1 = *(const float4*)(Wr + C2);
      float4 w2 = *(const float4*)(Wr + 2*C2);
      float4 w3 = *(const float4*)(Wr + 3*C2);
      acc.x += av.x*w0.x + av.y*w1.x + av.z*w2.x + av.w*w3.x;
      acc.y += av.x*w0.y + av.y*w1.y + av.z*w2.y + av.w*w3.y;
      acc.z += av.x*w0.z + av.y*w1.z + av.z*w2.z + av.w*w3.z;
      acc.w += av.x*w0.w + av.y*w1.w + av.z*w2.w + av.w*w3.w;
    }
    float4 o;
    o.x = lrelu(acc.x); o.y = lrelu(acc.y);
    o.z = lrelu(acc.z); o.w = lrelu(acc.w);
    *(float4*)(&buf[cb^1][r][c4]) = o;
    __syncthreads();
    cb ^= 1;
  }

  // head: 12 outputs (4 rows x 3 cols), one wave each; wave-shuffle reduce
  const int w = tid >> 6, lane = tid & 63;
  if (w < 12){
    const int rr = w / 3, c = w - rr*3;
    const float* cr = buf[cb][rr];
    float s = 0.f;
#pragma unroll
    for (int m=0;m<12;m++){
      int k = lane + 64*m;
      s += cr[k] * Wo[k*NL + c];
    }
#pragma unroll
    for (int off=1; off<64; off<<=1) s += __shfl_xor(s, off);
    if (lane == 0){
      float y = s + bo[c];
      if (c < 2) y = tanhf(y);
      out[(size_t)(blockIdx.x*4 + rr)*NL + c] = y;
    }
  }
}

// ------------------------------------------------------------------ launch --
extern "C" void kernel_launch(void* const* d_in, const int* in_sizes, int n_in,
                              void* d_out, int out_size, void* d_ws, size_t ws_size,
                              hipStream_t stream){
  const float* x   = (const float*)d_in[0];
  const float* Wc1 = (const float*)d_in[1];
  const float* bc1 = (const float*)d_in[2];
  const float* Wc2 = (const float*)d_in[3];
  const float* bc2 = (const float*)d_in[4];
  const float* Wc3 = (const float*)d_in[5];
  const float* bc3 = (const float*)d_in[6];
  const float* bng = (const float*)d_in[7];
  const float* bnb = (const float*)d_in[8];
  const float* W1  = (const float*)d_in[9];
  const float* b1  = (const float*)d_in[10];
  const float* W2  = (const float*)d_in[11];
  const float* b2  = (const float*)d_in[12];
  const float* W3  = (const float*)d_in[13];
  const float* b3  = (const float*)d_in[14];
  const float* W4  = (const float*)d_in[15];
  const float* b4  = (const float*)d_in[16];
  const float* W5  = (const float*)d_in[17];
  const float* b5  = (const float*)d_in[18];
  const float* Wo  = (const float*)d_in[19];
  const float* bo  = (const float*)d_in[20];

  char* ws = (char*)d_ws;
  size_t o = 0;
  int*   knn = (int*)  (ws + o); o += (size_t)NN*KNN*4;
  float* h0  = (float*)(ws + o); o += (size_t)NN*CC*4;
  float* h1  = (float*)(ws + o); o += (size_t)NN*CC*4;
  float* h2  = (float*)(ws + o); o += (size_t)NN*CC*4;
  float* gf  = (float*)(ws + o); o += (size_t)NB*C2*4;
  float* ax1 = h1;
  float* ax2 = h2;

  knn_kernel<<<NB*64, 256, 0, stream>>>(x, knn);

  const int tot7 = NN*FIN;
  agg7_kernel<<<(tot7+255)/256, 256, 0, stream>>>(x,   knn, ax1);
  agg7_kernel<<<(tot7+255)/256, 256, 0, stream>>>(ax1, knn, ax2);
  conv1_kernel<<<NN, CC, 0, stream>>>(x, ax1, ax2, Wc1, bc1, h0);
  pool_kernel<<<NB, 512, 0, stream>>>(h0, gf, 0);

  agg128_kernel<<<NN/4, 128, 0, stream>>>(h0, knn, h1);
  agg128_kernel<<<NN/4, 128, 0, stream>>>(h1, knn, h2);
  conv_gemm_kernel<<<NN/CMT, 256, 0, stream>>>(h0, h1, h2, Wc2, bc2, h1);
  pool_kernel<<<NB, 512, 0, stream>>>(h1, gf, 2*CC);

  agg128_kernel<<<NN/4, 128, 0, stream>>>(h1, knn, h0);
  agg128_kernel<<<NN/4, 128, 0, stream>>>(h0, knn, h2);
  conv_gemm_kernel<<<NN/CMT, 256, 0, stream>>>(h1, h0, h2, Wc3, bc3, h0);
  pool_kernel<<<NB, 512, 0, stream>>>(h0, gf, 4*CC);

  bn_kernel<<<12, 256, 0, stream>>>(gf, bng, bnb);

  mlp_fused_kernel<<<64, 768, 0, stream>>>(gf, W1,b1, W2,b2, W3,b3, W4,b4, W5,b5,
                                           Wo, bo, (float*)d_out);
}

// Round 4
// 980.198 us; speedup vs baseline: 1.0696x; 1.0696x over previous
//
#include <hip/hip_runtime.h>
#include <cstdint>
#include <cmath>

#define NB 256      // graphs (B)
#define MM 256      // nodes per graph
#define NN (NB*MM)  // 65536 nodes
#define KNN 15
#define FIN 7
#define CC 128
#define C2 768
#define NL 3
#define FINF 3.4e38f

__device__ __forceinline__ float lrelu(float v){ return v > 0.f ? v : 0.01f*v; }

// ---------------------------------------------------------------- kNN -------
// Wave-per-node, u64-packed keys: key = (f32bits(d2) << 32) | idx. d2 >= 0
// (clamped) so u32 ordering == f32 ordering; idx in the low bits gives the
// reference's lowest-index tie-break for free.
__global__ __launch_bounds__(256) void knn_kernel(const float* __restrict__ x,
                                                  int* __restrict__ knn){
  __shared__ float4 pos[MM];
  __shared__ float  sq[MM];
  const int g = blockIdx.x >> 6;               // 64 blocks per graph
  const int t = threadIdx.x;
  const float* xr = x + (size_t)(g*MM + t)*FIN;
  float4 p = make_float4(xr[0], xr[1], xr[2], xr[3]);
  pos[t] = p;
  sq[t]  = p.x*p.x + p.y*p.y + p.z*p.z + p.w*p.w;
  __syncthreads();

  const int i    = (blockIdx.x & 63)*4 + (t >> 6);  // local node this wave owns
  const int lane = t & 63;
  const float4 pi = pos[i];
  const float  sqi = sq[i];

  unsigned long long k[4];
#pragma unroll
  for (int q=0;q<4;q++){
    int j = q*64 + lane;
    float4 pj = pos[j];
    float dot = pi.x*pj.x + pi.y*pj.y + pi.z*pj.z + pi.w*pj.w;
    float d2 = fmaxf(sqi + sq[j] - 2.f*dot, 0.f);
    k[q] = ((unsigned long long)__float_as_uint(d2) << 32) | (unsigned)j;
    if (j == i) k[q] = ~0ull;                 // self-exclusion
  }

  int keep = 0;
#pragma unroll
  for (int it=0; it<KNN; it++){
    unsigned long long m01 = k[0] < k[1] ? k[0] : k[1];
    unsigned long long m23 = k[2] < k[3] ? k[2] : k[3];
    unsigned long long b   = m01  < m23  ? m01  : m23;
#pragma unroll
    for (int off=1; off<64; off<<=1){
      unsigned long long o = __shfl_xor(b, off);
      b = o < b ? o : b;
    }
    if (lane == it) keep = (int)(unsigned)b;  // low 32 bits = local idx j
#pragma unroll
    for (int q=0;q<4;q++) if (k[q] == b) k[q] = ~0ull;
  }
  if (lane < KNN)
    knn[(size_t)(g*MM + i)*KNN + lane] = g*MM + keep;
}

// ------------------------------------------------------------ aggregation ---
// norm is constant 1/15 (every node is dst exactly 15 times -> deg==15).
__global__ void agg7_kernel(const float* __restrict__ src,
                            const int* __restrict__ knn,
                            float* __restrict__ out){
  int i = blockIdx.x*blockDim.x + threadIdx.x;
  if (i >= NN*FIN) return;
  int n = i / FIN, c = i - n*FIN;
  const int* kn = knn + (size_t)n*KNN;
  float s = 0.f;
#pragma unroll
  for (int k=0;k<KNN;k++) s += src[(size_t)kn[k]*FIN + c];
  out[i] = s * (1.f/15.f);
}

__global__ __launch_bounds__(128) void agg128_kernel(const float* __restrict__ src,
                                                     const int* __restrict__ knn,
                                                     float* __restrict__ out){
  const int tid = threadIdx.x;
  const int n   = blockIdx.x*4 + (tid >> 5);
  const int c4  = (tid & 31) * 4;
  const int* kn = knn + (size_t)n*KNN;
  float4 s = make_float4(0.f,0.f,0.f,0.f);
#pragma unroll
  for (int k=0;k<KNN;k++){
    float4 v = *(const float4*)(src + (size_t)kn[k]*CC + c4);
    s.x += v.x; s.y += v.y; s.z += v.z; s.w += v.w;
  }
  float4 o = make_float4(s.x*(1.f/15.f), s.y*(1.f/15.f),
                         s.z*(1.f/15.f), s.w*(1.f/15.f));
  *(float4*)(out + (size_t)n*CC + c4) = o;
}

// ------------------------------------------------------------ conv layer 1 --
__global__ __launch_bounds__(128) void conv1_kernel(const float* __restrict__ x,
                                                    const float* __restrict__ a1,
                                                    const float* __restrict__ a2,
                                                    const float* __restrict__ W,
                                                    const float* __restrict__ b,
                                                    float* __restrict__ out){
  __shared__ float s[3*FIN];
  const int n = blockIdx.x, c = threadIdx.x;
  if (c < FIN)        s[c] = x [(size_t)n*FIN + c];
  else if (c < 2*FIN) s[c] = a1[(size_t)n*FIN + (c-FIN)];
  else if (c < 3*FIN) s[c] = a2[(size_t)n*FIN + (c-2*FIN)];
  __syncthreads();
  float acc = b[c];
#pragma unroll
  for (int t=0;t<3*FIN;t++) acc += s[t] * W[t*CC + c];
  out[(size_t)n*CC + c] = lrelu(acc);
}

// -------------------------------------------------- conv layers 2/3 (GEMM) --
#define CMT 64
__global__ __launch_bounds__(256) void conv_gemm_kernel(const float* __restrict__ p0,
                                                        const float* __restrict__ p1,
                                                        const float* __restrict__ p2,
                                                        const float* __restrict__ W,
                                                        const float* __restrict__ b,
                                                        float* __restrict__ out){
  __shared__ float Ast[32][CMT];   // [kk][r]
  __shared__ float Ws [32][CC];    // [kk][c]
  const int tid = threadIdx.x;
  const int row0 = blockIdx.x * CMT;
  const int tr = tid >> 5, tc = tid & 31;
  float acc[8][4];
#pragma unroll
  for (int i=0;i<8;i++)
#pragma unroll
    for (int j=0;j<4;j++) acc[i][j]=0.f;

#pragma unroll
  for (int hop=0; hop<3; hop++){
    const float* A  = (hop==0 ? p0 : hop==1 ? p1 : p2) + (size_t)row0*CC;
    const float* Wh = W + (size_t)hop*CC*CC;
    for (int kt=0; kt<4; kt++){
      __syncthreads();
#pragma unroll
      for (int q=0;q<2;q++){
        int chunk = tid + q*256;
        int r   = chunk >> 3;
        int kc4 = (chunk & 7) * 4;
        float4 v = *(const float4*)(A + (size_t)r*CC + kt*32 + kc4);
        Ast[kc4+0][r] = v.x; Ast[kc4+1][r] = v.y;
        Ast[kc4+2][r] = v.z; Ast[kc4+3][r] = v.w;
      }
#pragma unroll
      for (int q=0;q<4;q++){
        int chunk = tid + q*256;
        int kr = chunk >> 5;
        int c4 = (chunk & 31) * 4;
        *(float4*)(&Ws[kr][c4]) = *(const float4*)(Wh + (size_t)(kt*32+kr)*CC + c4);
      }
      __syncthreads();
#pragma unroll 8
      for (int kk=0;kk<32;kk++){
        float4 w  = *(const float4*)(&Ws[kk][tc*4]);
        float4 a0 = *(const float4*)(&Ast[kk][tr*8]);
        float4 a1 = *(const float4*)(&Ast[kk][tr*8+4]);
        float av[8] = {a0.x,a0.y,a0.z,a0.w,a1.x,a1.y,a1.z,a1.w};
        float wv[4] = {w.x,w.y,w.z,w.w};
#pragma unroll
        for (int i=0;i<8;i++)
#pragma unroll
          for (int j=0;j<4;j++) acc[i][j] += av[i]*wv[j];
      }
    }
  }
  const int c0 = tc*4;
  float4 bv = *(const float4*)(b + c0);
  float bb[4] = {bv.x,bv.y,bv.z,bv.w};
#pragma unroll
  for (int i=0;i<8;i++){
    int r = row0 + tr*8 + i;
    float4 o;
    o.x = lrelu(acc[i][0]+bb[0]);
    o.y = lrelu(acc[i][1]+bb[1]);
    o.z = lrelu(acc[i][2]+bb[2]);
    o.w = lrelu(acc[i][3]+bb[3]);
    *(float4*)(out + (size_t)r*CC + c0) = o;
  }
}

// ------------------------------------------------------------------ pooling -
__global__ __launch_bounds__(512) void pool_kernel(const float* __restrict__ h,
                                                   float* __restrict__ gf, int off){
  __shared__ float smean[4][CC];
  __shared__ float smax [4][CC];
  const int g = blockIdx.x, tid = threadIdx.x;
  const int c = tid & 127, grp = tid >> 7;
  const float* hp = h + (size_t)g*MM*CC + c;
  float s = 0.f, mx = -FINF;
  for (int m=grp*64; m<grp*64+64; m++){
    float v = hp[(size_t)m*CC];
    s += v; mx = fmaxf(mx, v);
  }
  smean[grp][c] = s; smax[grp][c] = mx;
  __syncthreads();
  if (grp == 0){
    s  = smean[0][c] + smean[1][c] + smean[2][c] + smean[3][c];
    mx = fmaxf(fmaxf(smax[0][c], smax[1][c]), fmaxf(smax[2][c], smax[3][c]));
    gf[(size_t)g*C2 + off + c]      = s * (1.f/MM);
    gf[(size_t)g*C2 + off + CC + c] = mx;
  }
}

// ---------------------------------------------------------------- batchnorm -
__global__ __launch_bounds__(256) void bn_kernel(float* __restrict__ g,
                                                 const float* __restrict__ gamma,
                                                 const float* __restrict__ beta){
  __shared__ float ssum[4][64], ssq[4][64], ssc[64], ssh[64];
  const int cl = threadIdx.x & 63, rg = threadIdx.x >> 6;
  const int c  = blockIdx.x*64 + cl;
  float s=0.f, q=0.f;
  for (int r=rg*64; r<rg*64+64; r++){
    float v = g[(size_t)r*C2 + c];
    s += v; q += v*v;
  }
  ssum[rg][cl]=s; ssq[rg][cl]=q;
  __syncthreads();
  if (rg == 0){
    s = ssum[0][cl]+ssum[1][cl]+ssum[2][cl]+ssum[3][cl];
    q = ssq [0][cl]+ssq [1][cl]+ssq [2][cl]+ssq [3][cl];
    float mu  = s * (1.f/NB);
    float var = q * (1.f/NB) - mu*mu;
    float sc  = rsqrtf(var + 1e-5f) * gamma[c];
    ssc[cl] = sc;
    ssh[cl] = beta[c] - mu*sc;
  }
  __syncthreads();
  const float sc = ssc[cl], sh = ssh[cl];
  for (int r=rg*64; r<rg*64+64; r++){
    size_t ix = (size_t)r*C2 + c;
    g[ix] = g[ix]*sc + sh;
  }
}

// -------------------------------------------------------------- MLP (GEMM) --
// out[256 x 768] = lrelu(A @ W + b). Tile 16 rows x 128 cols, grid (6,16).
__global__ __launch_bounds__(256) void mlp_gemm_kernel(const float* __restrict__ A,
                                                       const float* __restrict__ W,
                                                       const float* __restrict__ b,
                                                       float* __restrict__ out){
  __shared__ float Ast[32][16];
  __shared__ float Ws [32][128];
  const int tid = threadIdx.x;
  const int row0 = blockIdx.y * 16;
  const int col0 = blockIdx.x * 128;
  const int tr = tid >> 5, tc = tid & 31;
  float acc[2][4] = {{0.f,0.f,0.f,0.f},{0.f,0.f,0.f,0.f}};
  for (int kt=0; kt<24; kt++){
    __syncthreads();
    if (tid < 128){
      int r   = tid >> 3;
      int kc4 = (tid & 7)*4;
      float4 v = *(const float4*)(A + (size_t)(row0+r)*C2 + kt*32 + kc4);
      Ast[kc4+0][r]=v.x; Ast[kc4+1][r]=v.y; Ast[kc4+2][r]=v.z; Ast[kc4+3][r]=v.w;
    }
#pragma unroll
    for (int q=0;q<4;q++){
      int chunk = tid + q*256;
      int kr = chunk >> 5;
      int c4 = (chunk & 31)*4;
      *(float4*)(&Ws[kr][c4]) = *(const float4*)(W + (size_t)(kt*32+kr)*C2 + col0 + c4);
    }
    __syncthreads();
#pragma unroll 8
    for (int kk=0;kk<32;kk++){
      float4 w = *(const float4*)(&Ws[kk][tc*4]);
      float a0 = Ast[kk][tr*2+0];
      float a1 = Ast[kk][tr*2+1];
      acc[0][0] += a0*w.x; acc[0][1] += a0*w.y; acc[0][2] += a0*w.z; acc[0][3] += a0*w.w;
      acc[1][0] += a1*w.x; acc[1][1] += a1*w.y; acc[1][2] += a1*w.z; acc[1][3] += a1*w.w;
    }
  }
  const int c0 = col0 + tc*4;
  float4 bv = *(const float4*)(b + c0);
#pragma unroll
  for (int i=0;i<2;i++){
    int r = row0 + tr*2 + i;
    float4 o;
    o.x = lrelu(acc[i][0]+bv.x);
    o.y = lrelu(acc[i][1]+bv.y);
    o.z = lrelu(acc[i][2]+bv.z);
    o.w = lrelu(acc[i][3]+bv.w);
    *(float4*)(out + (size_t)r*C2 + c0) = o;
  }
}

// ------------------------------------------------------------- final layer --
__global__ __launch_bounds__(256) void final_kernel(const float* __restrict__ g,
                                                    const float* __restrict__ Wo,
                                                    const float* __restrict__ bo,
                                                    float* __restrict__ out){
  int i = blockIdx.x*256 + threadIdx.x;   // 0..767
  if (i >= NB*NL) return;
  int r = i / NL, c = i - r*NL;
  const float* gr = g + (size_t)r*C2;
  float acc = bo[c];
  for (int k=0;k<C2;k++) acc += gr[k]*Wo[k*NL + c];
  if (c < 2) acc = tanhf(acc);
  out[i] = acc;
}

// ------------------------------------------------------------------ launch --
extern "C" void kernel_launch(void* const* d_in, const int* in_sizes, int n_in,
                              void* d_out, int out_size, void* d_ws, size_t ws_size,
                              hipStream_t stream){
  const float* x   = (const float*)d_in[0];
  const float* Wc1 = (const float*)d_in[1];
  const float* bc1 = (const float*)d_in[2];
  const float* Wc2 = (const float*)d_in[3];
  const float* bc2 = (const float*)d_in[4];
  const float* Wc3 = (const float*)d_in[5];
  const float* bc3 = (const float*)d_in[6];
  const float* bng = (const float*)d_in[7];
  const float* bnb = (const float*)d_in[8];
  const float* W1  = (const float*)d_in[9];
  const float* b1  = (const float*)d_in[10];
  const float* W2  = (const float*)d_in[11];
  const float* b2  = (const float*)d_in[12];
  const float* W3  = (const float*)d_in[13];
  const float* b3  = (const float*)d_in[14];
  const float* W4  = (const float*)d_in[15];
  const float* b4  = (const float*)d_in[16];
  const float* W5  = (const float*)d_in[17];
  const float* b5  = (const float*)d_in[18];
  const float* Wo  = (const float*)d_in[19];
  const float* bo  = (const float*)d_in[20];

  char* ws = (char*)d_ws;
  size_t o = 0;
  int*   knn = (int*)  (ws + o); o += (size_t)NN*KNN*4;
  float* h0  = (float*)(ws + o); o += (size_t)NN*CC*4;
  float* h1  = (float*)(ws + o); o += (size_t)NN*CC*4;
  float* h2  = (float*)(ws + o); o += (size_t)NN*CC*4;
  float* gf  = (float*)(ws + o); o += (size_t)NB*C2*4;
  float* gt  = (float*)(ws + o); o += (size_t)NB*C2*4;
  float* ax1 = h1;
  float* ax2 = h2;

  knn_kernel<<<NB*64, 256, 0, stream>>>(x, knn);

  const int tot7 = NN*FIN;
  agg7_kernel<<<(tot7+255)/256, 256, 0, stream>>>(x,   knn, ax1);
  agg7_kernel<<<(tot7+255)/256, 256, 0, stream>>>(ax1, knn, ax2);
  conv1_kernel<<<NN, CC, 0, stream>>>(x, ax1, ax2, Wc1, bc1, h0);
  pool_kernel<<<NB, 512, 0, stream>>>(h0, gf, 0);

  agg128_kernel<<<NN/4, 128, 0, stream>>>(h0, knn, h1);
  agg128_kernel<<<NN/4, 128, 0, stream>>>(h1, knn, h2);
  conv_gemm_kernel<<<NN/CMT, 256, 0, stream>>>(h0, h1, h2, Wc2, bc2, h1);
  pool_kernel<<<NB, 512, 0, stream>>>(h1, gf, 2*CC);

  agg128_kernel<<<NN/4, 128, 0, stream>>>(h1, knn, h0);
  agg128_kernel<<<NN/4, 128, 0, stream>>>(h0, knn, h2);
  conv_gemm_kernel<<<NN/CMT, 256, 0, stream>>>(h1, h0, h2, Wc3, bc3, h0);
  pool_kernel<<<NB, 512, 0, stream>>>(h0, gf, 4*CC);

  bn_kernel<<<12, 256, 0, stream>>>(gf, bng, bnb);

  dim3 mgrid(6, 16);
  mlp_gemm_kernel<<<mgrid, 256, 0, stream>>>(gf, W1, b1, gt);
  mlp_gemm_kernel<<<mgrid, 256, 0, stream>>>(gt, W2, b2, gf);
  mlp_gemm_kernel<<<mgrid, 256, 0, stream>>>(gf, W3, b3, gt);
  mlp_gemm_kernel<<<mgrid, 256, 0, stream>>>(gt, W4, b4, gf);
  mlp_gemm_kernel<<<mgrid, 256, 0, stream>>>(gf, W5, b5, gt);

  final_kernel<<<3, 256, 0, stream>>>(gt, Wo, bo, (float*)d_out);
}

// Round 7
// 704.046 us; speedup vs baseline: 1.4892x; 1.3922x over previous
//
#include <hip/hip_runtime.h>
#include <cstdint>
#include <cmath>

#define NB 256      // graphs (B)
#define MM 256      // nodes per graph
#define NN (NB*MM)  // 65536 nodes
#define KNN 15
#define FIN 7
#define CC 128
#define C2 768
#define NL 3
#define FINF 3.4e38f

__device__ __forceinline__ float lrelu(float v){ return v > 0.f ? v : 0.01f*v; }

// bf16 helpers (RNE round; storage = unsigned short)
__device__ __forceinline__ unsigned short f2bf(float f){
  unsigned u = __float_as_uint(f);
  return (unsigned short)((u + 0x7FFFu + ((u >> 16) & 1u)) >> 16);
}
__device__ __forceinline__ float bf2f(unsigned short h){
  return __uint_as_float(((unsigned)h) << 16);
}

typedef short bf16x8 __attribute__((ext_vector_type(8)));
typedef float f32x4  __attribute__((ext_vector_type(4)));

// ---------------------------------------------------------------- kNN -------
// R2-exact version (measured 142 us, VALUBusy 76%). R4's u64-key variant was
// SLOWER (229 us, VALU 34%): fewer VALU ops but 2x ds_swizzle per step on the
// 64b value doubled the dependent-latency chain. Keep float+idx compare.
__global__ __launch_bounds__(256) void knn_kernel(const float* __restrict__ x,
                                                  int* __restrict__ knn){
  __shared__ float4 pos[MM];
  __shared__ float  sq[MM];
  const int g = blockIdx.x >> 6;               // 64 blocks per graph
  const int t = threadIdx.x;
  const float* xr = x + (size_t)(g*MM + t)*FIN;
  float4 p = make_float4(xr[0], xr[1], xr[2], xr[3]);
  pos[t] = p;
  sq[t]  = p.x*p.x + p.y*p.y + p.z*p.z + p.w*p.w;
  __syncthreads();

  const int i    = (blockIdx.x & 63)*4 + (t >> 6);  // local node this wave owns
  const int lane = t & 63;
  const float4 pi = pos[i];
  const float  sqi = sq[i];

  float d[4];
#pragma unroll
  for (int q=0;q<4;q++){
    int j = q*64 + lane;
    float4 pj = pos[j];
    float dot = pi.x*pj.x + pi.y*pj.y + pi.z*pj.z + pi.w*pj.w;
    d[q] = sqi + sq[j] - 2.f*dot;
    if (j == i) d[q] = FINF;                  // self-exclusion
  }

  int keep = 0;
#pragma unroll
  for (int it=0; it<KNN; it++){
    float lm = d[0]; int lq = 0;
    if (d[1] < lm){ lm = d[1]; lq = 1; }
    if (d[2] < lm){ lm = d[2]; lq = 2; }
    if (d[3] < lm){ lm = d[3]; lq = 3; }
    float bd = lm; int bi = lq*64 + lane;
#pragma unroll
    for (int off=1; off<64; off<<=1){
      float od = __shfl_xor(bd, off);
      int   oi = __shfl_xor(bi, off);
      if (od < bd || (od == bd && oi < bi)){ bd = od; bi = oi; }
    }
    if (lane == it) keep = bi;
#pragma unroll
    for (int q=0;q<4;q++) if (bi == q*64 + lane) d[q] = FINF;
  }
  if (lane < KNN)
    knn[(size_t)(g*MM + i)*KNN + lane] = g*MM + keep;
}

// ------------------------------------------------------------ aggregation ---
// norm is constant 1/15 (every node is dst exactly 15 times -> deg==15).
__global__ void agg7_kernel(const float* __restrict__ src,
                            const int* __restrict__ knn,
                            float* __restrict__ out){
  int i = blockIdx.x*blockDim.x + threadIdx.x;
  if (i >= NN*FIN) return;
  int n = i / FIN, c = i - n*FIN;
  const int* kn = knn + (size_t)n*KNN;
  float s = 0.f;
#pragma unroll
  for (int k=0;k<KNN;k++) s += src[(size_t)kn[k]*FIN + c];
  out[i] = s * (1.f/15.f);
}

// bf16 h: 8 nodes/block, 16 lanes x 8 channels = 128 per node (R5/R6 BUG:
// 32 lanes x 8 = 256 > CC -> half of every row read/written out of bounds,
// deterministic absmax 1.35. 16 lanes is the correct tiling.)
__global__ __launch_bounds__(128) void agg128_kernel(const unsigned short* __restrict__ src,
                                                     const int* __restrict__ knn,
                                                     unsigned short* __restrict__ out){
  const int tid = threadIdx.x;
  const int n   = blockIdx.x*8 + (tid >> 4);
  const int c8  = (tid & 15) * 8;
  const int* kn = knn + (size_t)n*KNN;
  float s[8];
#pragma unroll
  for (int e=0;e<8;e++) s[e]=0.f;
#pragma unroll
  for (int k=0;k<KNN;k++){
    uint4 r = *(const uint4*)(src + (size_t)kn[k]*CC + c8);
    s[0] += __uint_as_float(r.x << 16); s[1] += __uint_as_float(r.x & 0xFFFF0000u);
    s[2] += __uint_as_float(r.y << 16); s[3] += __uint_as_float(r.y & 0xFFFF0000u);
    s[4] += __uint_as_float(r.z << 16); s[5] += __uint_as_float(r.z & 0xFFFF0000u);
    s[6] += __uint_as_float(r.w << 16); s[7] += __uint_as_float(r.w & 0xFFFF0000u);
  }
  const float inv = 1.f/15.f;
  uint4 o;
  o.x = (unsigned)f2bf(s[0]*inv) | ((unsigned)f2bf(s[1]*inv) << 16);
  o.y = (unsigned)f2bf(s[2]*inv) | ((unsigned)f2bf(s[3]*inv) << 16);
  o.z = (unsigned)f2bf(s[4]*inv) | ((unsigned)f2bf(s[5]*inv) << 16);
  o.w = (unsigned)f2bf(s[6]*inv) | ((unsigned)f2bf(s[7]*inv) << 16);
  *(uint4*)(out + (size_t)n*CC + c8) = o;
}

// ------------------------------------------------------------ conv layer 1 --
// fp32 math, bf16 output (feeds the bf16 h-pipeline).
__global__ __launch_bounds__(128) void conv1_kernel(const float* __restrict__ x,
                                                    const float* __restrict__ a1,
                                                    const float* __restrict__ a2,
                                                    const float* __restrict__ W,
                                                    const float* __restrict__ b,
                                                    unsigned short* __restrict__ out){
  __shared__ float s[3*FIN];
  const int n = blockIdx.x, c = threadIdx.x;
  if (c < FIN)        s[c] = x [(size_t)n*FIN + c];
  else if (c < 2*FIN) s[c] = a1[(size_t)n*FIN + (c-FIN)];
  else if (c < 3*FIN) s[c] = a2[(size_t)n*FIN + (c-2*FIN)];
  __syncthreads();
  float acc = b[c];
#pragma unroll
  for (int t=0;t<3*FIN;t++) acc += s[t] * W[t*CC + c];
  out[(size_t)n*CC + c] = f2bf(lrelu(acc));
}

// ----------------------------------------------- pack W into B-frag order ---
// Wsrc fp32 [3][128][128] (hop,k,n) -> Wdst bf16 [(ck*4+q)*128 + n][8] where
// global k' = hop*128+k = ck*32 + q*8 + j. Lane (n, q) then loads its 8
// k-values as one contiguous 16B read.
__global__ void packW_kernel(const float* __restrict__ Wsrc,
                             unsigned short* __restrict__ Wdst){
  int idx = blockIdx.x*256 + threadIdx.x;   // [0, 3*128*128)
  if (idx >= 3*CC*CC) return;
  int kg = idx >> 7;           // hop*128 + k  (0..383)
  int n  = idx & 127;
  int ck = kg >> 5, q = (kg >> 3) & 3, j = kg & 7;
  Wdst[(((ck*4 + q)*CC) + n)*8 + j] = f2bf(Wsrc[idx]);
}

// -------------------------------------------- conv layers 2/3 (bf16 MFMA) ---
// out[N x 128] = lrelu( sum_hop A_hop @ W_hop + b ). 128x128 block tile,
// 4 waves of 64rows x 64cols, mfma_f32_16x16x32_bf16, K = 384 = 12 chunks.
// A-frag: lane holds A[m=lane&15][k = q*8 + j] -> 16B row-major global load.
// B-frag: lane holds B[k=q*8+j][n=lane&15]    -> 16B load from packed Wpk.
// C/D: col=lane&15, row=q*4+reg (m89/m91-verified).
// out must NOT alias p0/p1/p2 (no barrier before the epilogue writes).
__global__ __launch_bounds__(256) void conv_mfma_kernel(
    const unsigned short* __restrict__ p0,
    const unsigned short* __restrict__ p1,
    const unsigned short* __restrict__ p2,
    const unsigned short* __restrict__ Wpk,
    const float* __restrict__ bias,
    unsigned short* __restrict__ out){
  const int tid  = threadIdx.x;
  const int wv   = tid >> 6, lane = tid & 63;
  const int n    = lane & 15, q = lane >> 4;
  const int rows0 = blockIdx.x*128 + (wv & 1)*64;
  const int cols0 = (wv >> 1)*64;

  f32x4 acc[4][4];
#pragma unroll
  for (int i=0;i<4;i++)
#pragma unroll
    for (int t=0;t<4;t++) acc[i][t] = (f32x4){0.f,0.f,0.f,0.f};

#pragma unroll
  for (int ck=0; ck<12; ck++){
    const unsigned short* A = (ck < 4) ? p0 : (ck < 8) ? p1 : p2;
    const int kc = ck & 3;
    const unsigned short* ab = A + (size_t)(rows0 + n)*CC + kc*32 + q*8;
    bf16x8 af[4];
#pragma unroll
    for (int i=0;i<4;i++) af[i] = *(const bf16x8*)(ab + (size_t)i*16*CC);
    const unsigned short* wb = Wpk + ((size_t)(ck*4 + q)*CC + cols0 + n)*8;
    bf16x8 bf[4];
#pragma unroll
    for (int t=0;t<4;t++) bf[t] = *(const bf16x8*)(wb + t*16*8);
#pragma unroll
    for (int i=0;i<4;i++)
#pragma unroll
      for (int t=0;t<4;t++)
        acc[i][t] = __builtin_amdgcn_mfma_f32_16x16x32_bf16(af[i], bf[t], acc[i][t], 0, 0, 0);
  }

  float bv[4];
#pragma unroll
  for (int t=0;t<4;t++) bv[t] = bias[cols0 + t*16 + n];
#pragma unroll
  for (int i=0;i<4;i++){
#pragma unroll
    for (int t=0;t<4;t++){
#pragma unroll
      for (int r=0;r<4;r++){
        int row = rows0 + i*16 + q*4 + r;
        int col = cols0 + t*16 + n;
        out[(size_t)row*CC + col] = f2bf(lrelu(acc[i][t][r] + bv[t]));
      }
    }
  }
}

// ------------------------------------------------------------------ pooling -
__global__ __launch_bounds__(512) void pool_kernel(const unsigned short* __restrict__ h,
                                                   float* __restrict__ gf, int off){
  __shared__ float smean[4][CC];
  __shared__ float smax [4][CC];
  const int g = blockIdx.x, tid = threadIdx.x;
  const int c = tid & 127, grp = tid >> 7;
  const unsigned short* hp = h + (size_t)g*MM*CC + c;
  float s = 0.f, mx = -FINF;
  for (int m=grp*64; m<grp*64+64; m++){
    float v = bf2f(hp[(size_t)m*CC]);
    s += v; mx = fmaxf(mx, v);
  }
  smean[grp][c] = s; smax[grp][c] = mx;
  __syncthreads();
  if (grp == 0){
    s  = smean[0][c] + smean[1][c] + smean[2][c] + smean[3][c];
    mx = fmaxf(fmaxf(smax[0][c], smax[1][c]), fmaxf(smax[2][c], smax[3][c]));
    gf[(size_t)g*C2 + off + c]      = s * (1.f/MM);
    gf[(size_t)g*C2 + off + CC + c] = mx;
  }
}

// ---------------------------------------------------------------- batchnorm -
__global__ __launch_bounds__(256) void bn_kernel(float* __restrict__ g,
                                                 const float* __restrict__ gamma,
                                                 const float* __restrict__ beta){
  __shared__ float ssum[4][64], ssq[4][64], ssc[64], ssh[64];
  const int cl = threadIdx.x & 63, rg = threadIdx.x >> 6;
  const int c  = blockIdx.x*64 + cl;
  float s=0.f, q=0.f;
  for (int r=rg*64; r<rg*64+64; r++){
    float v = g[(size_t)r*C2 + c];
    s += v; q += v*v;
  }
  ssum[rg][cl]=s; ssq[rg][cl]=q;
  __syncthreads();
  if (rg == 0){
    s = ssum[0][cl]+ssum[1][cl]+ssum[2][cl]+ssum[3][cl];
    q = ssq [0][cl]+ssq [1][cl]+ssq [2][cl]+ssq [3][cl];
    float mu  = s * (1.f/NB);
    float var = q * (1.f/NB) - mu*mu;
    float sc  = rsqrtf(var + 1e-5f) * gamma[c];
    ssc[cl] = sc;
    ssh[cl] = beta[c] - mu*sc;
  }
  __syncthreads();
  const float sc = ssc[cl], sh = ssh[cl];
  for (int r=rg*64; r<rg*64+64; r++){
    size_t ix = (size_t)r*C2 + c;
    g[ix] = g[ix]*sc + sh;
  }
}

// -------------------------------------------------------------- MLP (GEMM) --
__global__ __launch_bounds__(256) void mlp_gemm_kernel(const float* __restrict__ A,
                                                       const float* __restrict__ W,
                                                       const float* __restrict__ b,
                                                       float* __restrict__ out){
  __shared__ float Ast[32][16];
  __shared__ float Ws [32][128];
  const int tid = threadIdx.x;
  const int row0 = blockIdx.y * 16;
  const int col0 = blockIdx.x * 128;
  const int tr = tid >> 5, tc = tid & 31;
  float acc[2][4] = {{0.f,0.f,0.f,0.f},{0.f,0.f,0.f,0.f}};
  for (int kt=0; kt<24; kt++){
    __syncthreads();
    if (tid < 128){
      int r   = tid >> 3;
      int kc4 = (tid & 7)*4;
      float4 v = *(const float4*)(A + (size_t)(row0+r)*C2 + kt*32 + kc4);
      Ast[kc4+0][r]=v.x; Ast[kc4+1][r]=v.y; Ast[kc4+2][r]=v.z; Ast[kc4+3][r]=v.w;
    }
#pragma unroll
    for (int q=0;q<4;q++){
      int chunk = tid + q*256;
      int kr = chunk >> 5;
      int c4 = (chunk & 31)*4;
      *(float4*)(&Ws[kr][c4]) = *(const float4*)(W + (size_t)(kt*32+kr)*C2 + col0 + c4);
    }
    __syncthreads();
#pragma unroll 8
    for (int kk=0;kk<32;kk++){
      float4 w = *(const float4*)(&Ws[kk][tc*4]);
      float a0 = Ast[kk][tr*2+0];
      float a1 = Ast[kk][tr*2+1];
      acc[0][0] += a0*w.x; acc[0][1] += a0*w.y; acc[0][2] += a0*w.z; acc[0][3] += a0*w.w;
      acc[1][0] += a1*w.x; acc[1][1] += a1*w.y; acc[1][2] += a1*w.z; acc[1][3] += a1*w.w;
    }
  }
  const int c0 = col0 + tc*4;
  float4 bv = *(const float4*)(b + c0);
#pragma unroll
  for (int i=0;i<2;i++){
    int r = row0 + tr*2 + i;
    float4 o;
    o.x = lrelu(acc[i][0]+bv.x);
    o.y = lrelu(acc[i][1]+bv.y);
    o.z = lrelu(acc[i][2]+bv.z);
    o.w = lrelu(acc[i][3]+bv.w);
    *(float4*)(out + (size_t)r*C2 + c0) = o;
  }
}

// ------------------------------------------------------------- final layer --
__global__ __launch_bounds__(256) void final_kernel(const float* __restrict__ g,
                                                    const float* __restrict__ Wo,
                                                    const float* __restrict__ bo,
                                                    float* __restrict__ out){
  int i = blockIdx.x*256 + threadIdx.x;   // 0..767
  if (i >= NB*NL) return;
  int r = i / NL, c = i - r*NL;
  const float* gr = g + (size_t)r*C2;
  float acc = bo[c];
  for (int k=0;k<C2;k++) acc += gr[k]*Wo[k*NL + c];
  if (c < 2) acc = tanhf(acc);
  out[i] = acc;
}

// ------------------------------------------------------------------ launch --
extern "C" void kernel_launch(void* const* d_in, const int* in_sizes, int n_in,
                              void* d_out, int out_size, void* d_ws, size_t ws_size,
                              hipStream_t stream){
  const float* x   = (const float*)d_in[0];
  const float* Wc1 = (const float*)d_in[1];
  const float* bc1 = (const float*)d_in[2];
  const float* Wc2 = (const float*)d_in[3];
  const float* bc2 = (const float*)d_in[4];
  const float* Wc3 = (const float*)d_in[5];
  const float* bc3 = (const float*)d_in[6];
  const float* bng = (const float*)d_in[7];
  const float* bnb = (const float*)d_in[8];
  const float* W1  = (const float*)d_in[9];
  const float* b1  = (const float*)d_in[10];
  const float* W2  = (const float*)d_in[11];
  const float* b2  = (const float*)d_in[12];
  const float* W3  = (const float*)d_in[13];
  const float* b3  = (const float*)d_in[14];
  const float* W4  = (const float*)d_in[15];
  const float* b4  = (const float*)d_in[16];
  const float* W5  = (const float*)d_in[17];
  const float* b5  = (const float*)d_in[18];
  const float* Wo  = (const float*)d_in[19];
  const float* bo  = (const float*)d_in[20];

  char* ws = (char*)d_ws;
  size_t o = 0;
  int*            knn  = (int*)           (ws + o); o += (size_t)NN*KNN*4;   // 3.93 MB
  unsigned short* h0   = (unsigned short*)(ws + o); o += (size_t)NN*CC*2;    // 16.8 MB
  unsigned short* h1   = (unsigned short*)(ws + o); o += (size_t)NN*CC*2;
  unsigned short* h2   = (unsigned short*)(ws + o); o += (size_t)NN*CC*2;
  unsigned short* h3   = (unsigned short*)(ws + o); o += (size_t)NN*CC*2;
  float*          ax1  = (float*)         (ws + o); o += (size_t)NN*FIN*4;   // 1.84 MB
  float*          ax2  = (float*)         (ws + o); o += (size_t)NN*FIN*4;
  float*          gf   = (float*)         (ws + o); o += (size_t)NB*C2*4;
  float*          gt   = (float*)         (ws + o); o += (size_t)NB*C2*4;
  unsigned short* Wpk2 = (unsigned short*)(ws + o); o += (size_t)3*CC*CC*2;
  unsigned short* Wpk3 = (unsigned short*)(ws + o); o += (size_t)3*CC*CC*2;

  knn_kernel<<<NB*64, 256, 0, stream>>>(x, knn);
  packW_kernel<<<192, 256, 0, stream>>>(Wc2, Wpk2);
  packW_kernel<<<192, 256, 0, stream>>>(Wc3, Wpk3);

  const int tot7 = NN*FIN;
  agg7_kernel<<<(tot7+255)/256, 256, 0, stream>>>(x,   knn, ax1);
  agg7_kernel<<<(tot7+255)/256, 256, 0, stream>>>(ax1, knn, ax2);
  conv1_kernel<<<NN, CC, 0, stream>>>(x, ax1, ax2, Wc1, bc1, h0);
  pool_kernel<<<NB, 512, 0, stream>>>(h0, gf, 0);

  // layer 2: reads h0 -> writes h3 (no aliasing with inputs h0/h1/h2)
  agg128_kernel<<<NN/8, 128, 0, stream>>>(h0, knn, h1);
  agg128_kernel<<<NN/8, 128, 0, stream>>>(h1, knn, h2);
  conv_mfma_kernel<<<NN/128, 256, 0, stream>>>(h0, h1, h2, Wpk2, bc2, h3);
  pool_kernel<<<NB, 512, 0, stream>>>(h3, gf, 2*CC);

  // layer 3: reads h3 -> writes h0 (h0's layer-1 contents no longer needed)
  agg128_kernel<<<NN/8, 128, 0, stream>>>(h3, knn, h1);
  agg128_kernel<<<NN/8, 128, 0, stream>>>(h1, knn, h2);
  conv_mfma_kernel<<<NN/128, 256, 0, stream>>>(h3, h1, h2, Wpk3, bc3, h0);
  pool_kernel<<<NB, 512, 0, stream>>>(h0, gf, 4*CC);

  bn_kernel<<<12, 256, 0, stream>>>(gf, bng, bnb);

  dim3 mgrid(6, 16);
  mlp_gemm_kernel<<<mgrid, 256, 0, stream>>>(gf, W1, b1, gt);
  mlp_gemm_kernel<<<mgrid, 256, 0, stream>>>(gt, W2, b2, gf);
  mlp_gemm_kernel<<<mgrid, 256, 0, stream>>>(gf, W3, b3, gt);
  mlp_gemm_kernel<<<mgrid, 256, 0, stream>>>(gt, W4, b4, gf);
  mlp_gemm_kernel<<<mgrid, 256, 0, stream>>>(gf, W5, b5, gt);

  final_kernel<<<3, 256, 0, stream>>>(gt, Wo, bo, (float*)d_out);
}

// Round 8
// 680.984 us; speedup vs baseline: 1.5396x; 1.0339x over previous
//
#include <hip/hip_runtime.h>
#include <cstdint>
#include <cmath>

#define NB 256      // graphs (B)
#define MM 256      // nodes per graph
#define NN (NB*MM)  // 65536 nodes
#define KNN 15
#define FIN 7
#define CC 128
#define C2 768
#define NL 3
#define FINF 3.4e38f

__device__ __forceinline__ float lrelu(float v){ return v > 0.f ? v : 0.01f*v; }

// bf16 helpers (RNE round; storage = unsigned short)
__device__ __forceinline__ unsigned short f2bf(float f){
  unsigned u = __float_as_uint(f);
  return (unsigned short)((u + 0x7FFFu + ((u >> 16) & 1u)) >> 16);
}
__device__ __forceinline__ float bf2f(unsigned short h){
  return __uint_as_float(((unsigned)h) << 16);
}

typedef short bf16x8 __attribute__((ext_vector_type(8)));
typedef float f32x4  __attribute__((ext_vector_type(4)));

// ---------------------------------------------------------------- kNN -------
// Wave handles TWO nodes: the two independent butterfly chains interleave so
// node B's swizzles issue while node A's lgkm results are in flight (R7: 74%
// VALUBusy at 84% occupancy = dependent-swizzle stalls; this fills them).
// Selection arithmetic per node is IDENTICAL to R7 -> same neighbor sets.
// (R4 lesson: u64-packed keys = 2x swizzles per step, slower. Keep f32+idx.)
__global__ __launch_bounds__(256) void knn_kernel(const float* __restrict__ x,
                                                  int* __restrict__ knn){
  __shared__ float4 pos[MM];
  __shared__ float  sq[MM];
  const int g = blockIdx.x >> 5;               // 32 blocks per graph
  const int t = threadIdx.x;
  const float* xr = x + (size_t)(g*MM + t)*FIN;
  float4 p = make_float4(xr[0], xr[1], xr[2], xr[3]);
  pos[t] = p;
  sq[t]  = p.x*p.x + p.y*p.y + p.z*p.z + p.w*p.w;
  __syncthreads();

  const int lane = t & 63;
  const int i0 = (blockIdx.x & 31)*8 + (t >> 6)*2;   // this wave's two nodes
  const int i1 = i0 + 1;
  const float4 pA = pos[i0], pB = pos[i1];
  const float  sqA = sq[i0], sqB = sq[i1];

  float dA[4], dB[4];
#pragma unroll
  for (int q=0;q<4;q++){
    int j = q*64 + lane;
    float4 pj = pos[j];
    float sqj = sq[j];
    float dotA = pA.x*pj.x + pA.y*pj.y + pA.z*pj.z + pA.w*pj.w;
    float dotB = pB.x*pj.x + pB.y*pj.y + pB.z*pj.z + pB.w*pj.w;
    dA[q] = sqA + sqj - 2.f*dotA;
    dB[q] = sqB + sqj - 2.f*dotB;
    if (j == i0) dA[q] = FINF;                // self-exclusion
    if (j == i1) dB[q] = FINF;
  }

  int keepA = 0, keepB = 0;
#pragma unroll
  for (int it=0; it<KNN; it++){
    float lmA = dA[0]; int lqA = 0;
    if (dA[1] < lmA){ lmA = dA[1]; lqA = 1; }
    if (dA[2] < lmA){ lmA = dA[2]; lqA = 2; }
    if (dA[3] < lmA){ lmA = dA[3]; lqA = 3; }
    float lmB = dB[0]; int lqB = 0;
    if (dB[1] < lmB){ lmB = dB[1]; lqB = 1; }
    if (dB[2] < lmB){ lmB = dB[2]; lqB = 2; }
    if (dB[3] < lmB){ lmB = dB[3]; lqB = 3; }
    float bdA = lmA; int biA = lqA*64 + lane;
    float bdB = lmB; int biB = lqB*64 + lane;
#pragma unroll
    for (int off=1; off<64; off<<=1){
      float odA = __shfl_xor(bdA, off);
      int   oiA = __shfl_xor(biA, off);
      float odB = __shfl_xor(bdB, off);
      int   oiB = __shfl_xor(biB, off);
      if (odA < bdA || (odA == bdA && oiA < biA)){ bdA = odA; biA = oiA; }
      if (odB < bdB || (odB == bdB && oiB < biB)){ bdB = odB; biB = oiB; }
    }
    if (lane == it){ keepA = biA; keepB = biB; }
#pragma unroll
    for (int q=0;q<4;q++){
      if (biA == q*64 + lane) dA[q] = FINF;
      if (biB == q*64 + lane) dB[q] = FINF;
    }
  }
  if (lane < KNN){
    knn[(size_t)(g*MM + i0)*KNN + lane] = g*MM + keepA;
    knn[(size_t)(g*MM + i1)*KNN + lane] = g*MM + keepB;
  }
}

// ------------------------------------------------------------ aggregation ---
// norm is constant 1/15 (every node is dst exactly 15 times -> deg==15).
__global__ void agg7_kernel(const float* __restrict__ src,
                            const int* __restrict__ knn,
                            float* __restrict__ out){
  int i = blockIdx.x*blockDim.x + threadIdx.x;
  if (i >= NN*FIN) return;
  int n = i / FIN, c = i - n*FIN;
  const int* kn = knn + (size_t)n*KNN;
  float s = 0.f;
#pragma unroll
  for (int k=0;k<KNN;k++) s += src[(size_t)kn[k]*FIN + c];
  out[i] = s * (1.f/15.f);
}

// bf16 h: 8 nodes/block, 16 lanes x 8 channels = 128 per node.
// XCD-locality swizzle: blocks b = x (mod 8) land on XCD x (round-robin
// dispatch); remap so XCD x covers contiguous graphs [x*32, (x+1)*32) ->
// 2 MB working set per XCD fits its 4 MB L2 (unswizzled: every XCD thrashes
// the full 16.8 MB h-buffer through 4 MB). Per-node math order unchanged ->
// bit-identical output.
__global__ __launch_bounds__(128) void agg128_kernel(const unsigned short* __restrict__ src,
                                                     const int* __restrict__ knn,
                                                     unsigned short* __restrict__ out){
  const int tid = threadIdx.x;
  const int nb  = (blockIdx.x & 7) * 1024 + (blockIdx.x >> 3);  // 8192 blocks
  const int n   = nb*8 + (tid >> 4);
  const int c8  = (tid & 15) * 8;
  const int* kn = knn + (size_t)n*KNN;
  float s[8];
#pragma unroll
  for (int e=0;e<8;e++) s[e]=0.f;
#pragma unroll
  for (int k=0;k<KNN;k++){
    uint4 r = *(const uint4*)(src + (size_t)kn[k]*CC + c8);
    s[0] += __uint_as_float(r.x << 16); s[1] += __uint_as_float(r.x & 0xFFFF0000u);
    s[2] += __uint_as_float(r.y << 16); s[3] += __uint_as_float(r.y & 0xFFFF0000u);
    s[4] += __uint_as_float(r.z << 16); s[5] += __uint_as_float(r.z & 0xFFFF0000u);
    s[6] += __uint_as_float(r.w << 16); s[7] += __uint_as_float(r.w & 0xFFFF0000u);
  }
  const float inv = 1.f/15.f;
  uint4 o;
  o.x = (unsigned)f2bf(s[0]*inv) | ((unsigned)f2bf(s[1]*inv) << 16);
  o.y = (unsigned)f2bf(s[2]*inv) | ((unsigned)f2bf(s[3]*inv) << 16);
  o.z = (unsigned)f2bf(s[4]*inv) | ((unsigned)f2bf(s[5]*inv) << 16);
  o.w = (unsigned)f2bf(s[6]*inv) | ((unsigned)f2bf(s[7]*inv) << 16);
  *(uint4*)(out + (size_t)n*CC + c8) = o;
}

// ------------------------------------------------------------ conv layer 1 --
// fp32 math, bf16 output (feeds the bf16 h-pipeline).
__global__ __launch_bounds__(128) void conv1_kernel(const float* __restrict__ x,
                                                    const float* __restrict__ a1,
                                                    const float* __restrict__ a2,
                                                    const float* __restrict__ W,
                                                    const float* __restrict__ b,
                                                    unsigned short* __restrict__ out){
  __shared__ float s[3*FIN];
  const int n = blockIdx.x, c = threadIdx.x;
  if (c < FIN)        s[c] = x [(size_t)n*FIN + c];
  else if (c < 2*FIN) s[c] = a1[(size_t)n*FIN + (c-FIN)];
  else if (c < 3*FIN) s[c] = a2[(size_t)n*FIN + (c-2*FIN)];
  __syncthreads();
  float acc = b[c];
#pragma unroll
  for (int t=0;t<3*FIN;t++) acc += s[t] * W[t*CC + c];
  out[(size_t)n*CC + c] = f2bf(lrelu(acc));
}

// ----------------------------------------------- pack W into B-frag order ---
// Both conv weights in one dispatch. Wsrc fp32 [3][128][128] (hop,k,n) ->
// Wdst bf16 [(ck*4+q)*128 + n][8], k' = hop*128+k = ck*32 + q*8 + j.
__global__ void packW_kernel(const float* __restrict__ W2src,
                             const float* __restrict__ W3src,
                             unsigned short* __restrict__ W2dst,
                             unsigned short* __restrict__ W3dst){
  int idx = blockIdx.x*256 + threadIdx.x;   // [0, 2*3*128*128)
  if (idx >= 2*3*CC*CC) return;
  const float* Wsrc = (idx < 3*CC*CC) ? W2src : W3src;
  unsigned short* Wdst = (idx < 3*CC*CC) ? W2dst : W3dst;
  int e = (idx < 3*CC*CC) ? idx : idx - 3*CC*CC;
  int kg = e >> 7;             // hop*128 + k  (0..383)
  int n  = e & 127;
  int ck = kg >> 5, q = (kg >> 3) & 3, j = kg & 7;
  Wdst[(((ck*4 + q)*CC) + n)*8 + j] = f2bf(Wsrc[e]);
}

// -------------------------------------------- conv layers 2/3 (bf16 MFMA) ---
// out[N x 128] = lrelu( sum_hop A_hop @ W_hop + b ). 128x128 block tile,
// 4 waves of 64rows x 64cols, mfma_f32_16x16x32_bf16, K = 384 = 12 chunks.
// A-frag: lane holds A[m=lane&15][k = q*8 + j] -> 16B row-major global load.
// B-frag: lane holds B[k=q*8+j][n=lane&15]    -> 16B load from packed Wpk.
// C/D: col=lane&15, row=q*4+reg (m89/m91-verified).
// out must NOT alias p0/p1/p2 (no barrier before the epilogue writes).
__global__ __launch_bounds__(256) void conv_mfma_kernel(
    const unsigned short* __restrict__ p0,
    const unsigned short* __restrict__ p1,
    const unsigned short* __restrict__ p2,
    const unsigned short* __restrict__ Wpk,
    const float* __restrict__ bias,
    unsigned short* __restrict__ out){
  const int tid  = threadIdx.x;
  const int wv   = tid >> 6, lane = tid & 63;
  const int n    = lane & 15, q = lane >> 4;
  const int rows0 = blockIdx.x*128 + (wv & 1)*64;
  const int cols0 = (wv >> 1)*64;

  f32x4 acc[4][4];
#pragma unroll
  for (int i=0;i<4;i++)
#pragma unroll
    for (int t=0;t<4;t++) acc[i][t] = (f32x4){0.f,0.f,0.f,0.f};

#pragma unroll
  for (int ck=0; ck<12; ck++){
    const unsigned short* A = (ck < 4) ? p0 : (ck < 8) ? p1 : p2;
    const int kc = ck & 3;
    const unsigned short* ab = A + (size_t)(rows0 + n)*CC + kc*32 + q*8;
    bf16x8 af[4];
#pragma unroll
    for (int i=0;i<4;i++) af[i] = *(const bf16x8*)(ab + (size_t)i*16*CC);
    const unsigned short* wb = Wpk + ((size_t)(ck*4 + q)*CC + cols0 + n)*8;
    bf16x8 bf[4];
#pragma unroll
    for (int t=0;t<4;t++) bf[t] = *(const bf16x8*)(wb + t*16*8);
#pragma unroll
    for (int i=0;i<4;i++)
#pragma unroll
      for (int t=0;t<4;t++)
        acc[i][t] = __builtin_amdgcn_mfma_f32_16x16x32_bf16(af[i], bf[t], acc[i][t], 0, 0, 0);
  }

  float bv[4];
#pragma unroll
  for (int t=0;t<4;t++) bv[t] = bias[cols0 + t*16 + n];
#pragma unroll
  for (int i=0;i<4;i++){
#pragma unroll
    for (int t=0;t<4;t++){
#pragma unroll
      for (int r=0;r<4;r++){
        int row = rows0 + i*16 + q*4 + r;
        int col = cols0 + t*16 + n;
        out[(size_t)row*CC + col] = f2bf(lrelu(acc[i][t][r] + bv[t]));
      }
    }
  }
}

// ------------------------------------------------------------------ pooling -
__global__ __launch_bounds__(512) void pool_kernel(const unsigned short* __restrict__ h,
                                                   float* __restrict__ gf, int off){
  __shared__ float smean[4][CC];
  __shared__ float smax [4][CC];
  const int g = blockIdx.x, tid = threadIdx.x;
  const int c = tid & 127, grp = tid >> 7;
  const unsigned short* hp = h + (size_t)g*MM*CC + c;
  float s = 0.f, mx = -FINF;
  for (int m=grp*64; m<grp*64+64; m++){
    float v = bf2f(hp[(size_t)m*CC]);
    s += v; mx = fmaxf(mx, v);
  }
  smean[grp][c] = s; smax[grp][c] = mx;
  __syncthreads();
  if (grp == 0){
    s  = smean[0][c] + smean[1][c] + smean[2][c] + smean[3][c];
    mx = fmaxf(fmaxf(smax[0][c], smax[1][c]), fmaxf(smax[2][c], smax[3][c]));
    gf[(size_t)g*C2 + off + c]      = s * (1.f/MM);
    gf[(size_t)g*C2 + off + CC + c] = mx;
  }
}

// ---------------------------------------------------------------- batchnorm -
__global__ __launch_bounds__(256) void bn_kernel(float* __restrict__ g,
                                                 const float* __restrict__ gamma,
                                                 const float* __restrict__ beta){
  __shared__ float ssum[4][64], ssq[4][64], ssc[64], ssh[64];
  const int cl = threadIdx.x & 63, rg = threadIdx.x >> 6;
  const int c  = blockIdx.x*64 + cl;
  float s=0.f, q=0.f;
  for (int r=rg*64; r<rg*64+64; r++){
    float v = g[(size_t)r*C2 + c];
    s += v; q += v*v;
  }
  ssum[rg][cl]=s; ssq[rg][cl]=q;
  __syncthreads();
  if (rg == 0){
    s = ssum[0][cl]+ssum[1][cl]+ssum[2][cl]+ssum[3][cl];
    q = ssq [0][cl]+ssq [1][cl]+ssq [2][cl]+ssq [3][cl];
    float mu  = s * (1.f/NB);
    float var = q * (1.f/NB) - mu*mu;
    float sc  = rsqrtf(var + 1e-5f) * gamma[c];
    ssc[cl] = sc;
    ssh[cl] = beta[c] - mu*sc;
  }
  __syncthreads();
  const float sc = ssc[cl], sh = ssh[cl];
  for (int r=rg*64; r<rg*64+64; r++){
    size_t ix = (size_t)r*C2 + c;
    g[ix] = g[ix]*sc + sh;
  }
}

// -------------------------------------------------------------- MLP (GEMM) --
__global__ __launch_bounds__(256) void mlp_gemm_kernel(const float* __restrict__ A,
                                                       const float* __restrict__ W,
                                                       const float* __restrict__ b,
                                                       float* __restrict__ out){
  __shared__ float Ast[32][16];
  __shared__ float Ws [32][128];
  const int tid = threadIdx.x;
  const int row0 = blockIdx.y * 16;
  const int col0 = blockIdx.x * 128;
  const int tr = tid >> 5, tc = tid & 31;
  float acc[2][4] = {{0.f,0.f,0.f,0.f},{0.f,0.f,0.f,0.f}};
  for (int kt=0; kt<24; kt++){
    __syncthreads();
    if (tid < 128){
      int r   = tid >> 3;
      int kc4 = (tid & 7)*4;
      float4 v = *(const float4*)(A + (size_t)(row0+r)*C2 + kt*32 + kc4);
      Ast[kc4+0][r]=v.x; Ast[kc4+1][r]=v.y; Ast[kc4+2][r]=v.z; Ast[kc4+3][r]=v.w;
    }
#pragma unroll
    for (int q=0;q<4;q++){
      int chunk = tid + q*256;
      int kr = chunk >> 5;
      int c4 = (chunk & 31)*4;
      *(float4*)(&Ws[kr][c4]) = *(const float4*)(W + (size_t)(kt*32+kr)*C2 + col0 + c4);
    }
    __syncthreads();
#pragma unroll 8
    for (int kk=0;kk<32;kk++){
      float4 w = *(const float4*)(&Ws[kk][tc*4]);
      float a0 = Ast[kk][tr*2+0];
      float a1 = Ast[kk][tr*2+1];
      acc[0][0] += a0*w.x; acc[0][1] += a0*w.y; acc[0][2] += a0*w.z; acc[0][3] += a0*w.w;
      acc[1][0] += a1*w.x; acc[1][1] += a1*w.y; acc[1][2] += a1*w.z; acc[1][3] += a1*w.w;
    }
  }
  const int c0 = col0 + tc*4;
  float4 bv = *(const float4*)(b + c0);
#pragma unroll
  for (int i=0;i<2;i++){
    int r = row0 + tr*2 + i;
    float4 o;
    o.x = lrelu(acc[i][0]+bv.x);
    o.y = lrelu(acc[i][1]+bv.y);
    o.z = lrelu(acc[i][2]+bv.z);
    o.w = lrelu(acc[i][3]+bv.w);
    *(float4*)(out + (size_t)r*C2 + c0) = o;
  }
}

// ------------------------------------------------------------- final layer --
__global__ __launch_bounds__(256) void final_kernel(const float* __restrict__ g,
                                                    const float* __restrict__ Wo,
                                                    const float* __restrict__ bo,
                                                    float* __restrict__ out){
  int i = blockIdx.x*256 + threadIdx.x;   // 0..767
  if (i >= NB*NL) return;
  int r = i / NL, c = i - r*NL;
  const float* gr = g + (size_t)r*C2;
  float acc = bo[c];
  for (int k=0;k<C2;k++) acc += gr[k]*Wo[k*NL + c];
  if (c < 2) acc = tanhf(acc);
  out[i] = acc;
}

// ------------------------------------------------------------------ launch --
extern "C" void kernel_launch(void* const* d_in, const int* in_sizes, int n_in,
                              void* d_out, int out_size, void* d_ws, size_t ws_size,
                              hipStream_t stream){
  const float* x   = (const float*)d_in[0];
  const float* Wc1 = (const float*)d_in[1];
  const float* bc1 = (const float*)d_in[2];
  const float* Wc2 = (const float*)d_in[3];
  const float* bc2 = (const float*)d_in[4];
  const float* Wc3 = (const float*)d_in[5];
  const float* bc3 = (const float*)d_in[6];
  const float* bng = (const float*)d_in[7];
  const float* bnb = (const float*)d_in[8];
  const float* W1  = (const float*)d_in[9];
  const float* b1  = (const float*)d_in[10];
  const float* W2  = (const float*)d_in[11];
  const float* b2  = (const float*)d_in[12];
  const float* W3  = (const float*)d_in[13];
  const float* b3  = (const float*)d_in[14];
  const float* W4  = (const float*)d_in[15];
  const float* b4  = (const float*)d_in[16];
  const float* W5  = (const float*)d_in[17];
  const float* b5  = (const float*)d_in[18];
  const float* Wo  = (const float*)d_in[19];
  const float* bo  = (const float*)d_in[20];

  char* ws = (char*)d_ws;
  size_t o = 0;
  int*            knn  = (int*)           (ws + o); o += (size_t)NN*KNN*4;   // 3.93 MB
  unsigned short* h0   = (unsigned short*)(ws + o); o += (size_t)NN*CC*2;    // 16.8 MB
  unsigned short* h1   = (unsigned short*)(ws + o); o += (size_t)NN*CC*2;
  unsigned short* h2   = (unsigned short*)(ws + o); o += (size_t)NN*CC*2;
  unsigned short* h3   = (unsigned short*)(ws + o); o += (size_t)NN*CC*2;
  float*          ax1  = (float*)         (ws + o); o += (size_t)NN*FIN*4;   // 1.84 MB
  float*          ax2  = (float*)         (ws + o); o += (size_t)NN*FIN*4;
  float*          gf   = (float*)         (ws + o); o += (size_t)NB*C2*4;
  float*          gt   = (float*)         (ws + o); o += (size_t)NB*C2*4;
  unsigned short* Wpk2 = (unsigned short*)(ws + o); o += (size_t)3*CC*CC*2;
  unsigned short* Wpk3 = (unsigned short*)(ws + o); o += (size_t)3*CC*CC*2;

  knn_kernel<<<NB*32, 256, 0, stream>>>(x, knn);
  packW_kernel<<<384, 256, 0, stream>>>(Wc2, Wc3, Wpk2, Wpk3);

  const int tot7 = NN*FIN;
  agg7_kernel<<<(tot7+255)/256, 256, 0, stream>>>(x,   knn, ax1);
  agg7_kernel<<<(tot7+255)/256, 256, 0, stream>>>(ax1, knn, ax2);
  conv1_kernel<<<NN, CC, 0, stream>>>(x, ax1, ax2, Wc1, bc1, h0);
  pool_kernel<<<NB, 512, 0, stream>>>(h0, gf, 0);

  // layer 2: reads h0 -> writes h3 (no aliasing with inputs h0/h1/h2)
  agg128_kernel<<<NN/8, 128, 0, stream>>>(h0, knn, h1);
  agg128_kernel<<<NN/8, 128, 0, stream>>>(h1, knn, h2);
  conv_mfma_kernel<<<NN/128, 256, 0, stream>>>(h0, h1, h2, Wpk2, bc2, h3);
  pool_kernel<<<NB, 512, 0, stream>>>(h3, gf, 2*CC);

  // layer 3: reads h3 -> writes h0 (h0's layer-1 contents no longer needed)
  agg128_kernel<<<NN/8, 128, 0, stream>>>(h3, knn, h1);
  agg128_kernel<<<NN/8, 128, 0, stream>>>(h1, knn, h2);
  conv_mfma_kernel<<<NN/128, 256, 0, stream>>>(h3, h1, h2, Wpk3, bc3, h0);
  pool_kernel<<<NB, 512, 0, stream>>>(h0, gf, 4*CC);

  bn_kernel<<<12, 256, 0, stream>>>(gf, bng, bnb);

  dim3 mgrid(6, 16);
  mlp_gemm_kernel<<<mgrid, 256, 0, stream>>>(gf, W1, b1, gt);
  mlp_gemm_kernel<<<mgrid, 256, 0, stream>>>(gt, W2, b2, gf);
  mlp_gemm_kernel<<<mgrid, 256, 0, stream>>>(gf, W3, b3, gt);
  mlp_gemm_kernel<<<mgrid, 256, 0, stream>>>(gt, W4, b4, gf);
  mlp_gemm_kernel<<<mgrid, 256, 0, stream>>>(gf, W5, b5, gt);

  final_kernel<<<3, 256, 0, stream>>>(gt, Wo, bo, (float*)d_out);
}

// Round 9
// 585.379 us; speedup vs baseline: 1.7910x; 1.1633x over previous
//
#include <hip/hip_runtime.h>
#include <cstdint>
#include <cmath>

#define NB 256      // graphs (B)
#define MM 256      // nodes per graph
#define NN (NB*MM)  // 65536 nodes
#define KNN 15
#define FIN 7
#define CC 128
#define C2 768
#define NL 3
#define FINF 3.4e38f

__device__ __forceinline__ float lrelu(float v){ return v > 0.f ? v : 0.01f*v; }

// bf16 helpers (RNE round; storage = unsigned short)
__device__ __forceinline__ unsigned short f2bf(float f){
  unsigned u = __float_as_uint(f);
  return (unsigned short)((u + 0x7FFFu + ((u >> 16) & 1u)) >> 16);
}
__device__ __forceinline__ float bf2f(unsigned short h){
  return __uint_as_float(((unsigned)h) << 16);
}

__device__ __forceinline__ int mbcnt64(unsigned long long m){
  return (int)__builtin_amdgcn_mbcnt_hi((unsigned)(m >> 32),
              __builtin_amdgcn_mbcnt_lo((unsigned)m, 0u));
}

typedef short bf16x8 __attribute__((ext_vector_type(8)));
typedef float f32x4  __attribute__((ext_vector_type(4)));

// ---------------------------------------------------------------- kNN -------
// Radix-select rewrite. R2/R7 butterfly = 15 rounds x 6 swizzle-dependent
// steps ~600 issue-slots/node (issue-bound: R8's ILP interleave was neutral).
// Here: 32-step MSB binary search for the 15th-smallest key using __ballot +
// popcount only (4 v_cmp/step, counts on the scalar pipe, zero swizzles),
// then an exact (key,idx) rank-sort of the 15 winners through LDS so the
// output k-order is BIT-IDENTICAL to the butterfly version (aggregation sum
// order preserved -> absmax must not move; margin to threshold is only 6%).
// Key = sign-aware sortable-u32 of the UNMODIFIED d2 (no clamp), idx
// tie-break ascending = reference top_k semantics.
__global__ __launch_bounds__(256) void knn_kernel(const float* __restrict__ x,
                                                  int* __restrict__ knn){
  __shared__ float4 pos[MM];
  __shared__ float  sq[MM];
  __shared__ unsigned skey[4][16];
  __shared__ int      sidx[4][16];
  const int g = blockIdx.x >> 6;               // 64 blocks per graph
  const int t = threadIdx.x;
  const float* xr = x + (size_t)(g*MM + t)*FIN;
  float4 p = make_float4(xr[0], xr[1], xr[2], xr[3]);
  pos[t] = p;
  sq[t]  = p.x*p.x + p.y*p.y + p.z*p.z + p.w*p.w;
  __syncthreads();

  const int i    = (blockIdx.x & 63)*4 + (t >> 6);  // wave's node
  const int wv   = t >> 6;
  const int lane = t & 63;
  const float4 pi = pos[i];
  const float  sqi = sq[i];

  unsigned key[4];
#pragma unroll
  for (int q=0;q<4;q++){
    int j = q*64 + lane;
    float4 pj = pos[j];
    float dot = pi.x*pj.x + pi.y*pj.y + pi.z*pj.z + pi.w*pj.w;
    float d2  = sqi + sq[j] - 2.f*dot;          // exact reference arithmetic
    unsigned u = __float_as_uint(d2);
    u = ((int)u < 0) ? ~u : (u ^ 0x80000000u);  // monotone f32 -> u32
    key[q] = (j == i) ? 0xFFFFFFFFu : u;        // self-exclusion sentinel
  }

  // MSB-first binary search: K = 15th-smallest key (counting multiplicity).
  // Invariants: cnt(key < prefix) < 15, cnt(key < prefix + 2^(bit+1)) >= 15.
  unsigned prefix = 0u;
#pragma unroll
  for (int bit=31; bit>=0; --bit){
    unsigned trial = prefix | (1u << bit);
    int c = __popcll(__ballot(key[0] < trial))
          + __popcll(__ballot(key[1] < trial))
          + __popcll(__ballot(key[2] < trial))
          + __popcll(__ballot(key[3] < trial));
    if (c < KNN) prefix = trial;
  }
  const unsigned K = prefix;

  // winners = all key<K plus the (15 - cnt_lt) lowest-index key==K.
  int c_lt = __popcll(__ballot(key[0] < K)) + __popcll(__ballot(key[1] < K))
           + __popcll(__ballot(key[2] < K)) + __popcll(__ballot(key[3] < K));
  int need = KNN - c_lt;
  bool w[4];
  int eqbase = 0;
#pragma unroll
  for (int q=0;q<4;q++){
    unsigned long long em = __ballot(key[q] == K);
    int gr = eqbase + mbcnt64(em);              // global eq-rank (asc index)
    w[q] = (key[q] < K) || ((key[q] == K) && (gr < need));
    eqbase += __popcll(em);
  }

  // scatter winners (unsorted) to per-wave LDS scratch
  int base = 0;
#pragma unroll
  for (int q=0;q<4;q++){
    unsigned long long wm = __ballot(w[q]);
    int rk = mbcnt64(wm);
    if (w[q]){ skey[wv][base+rk] = key[q]; sidx[wv][base+rk] = q*64 + lane; }
    base += __popcll(wm);
  }
  __builtin_amdgcn_wave_barrier();              // wave-internal LDS RAW fence

  // exact (key, idx) rank -> emit ascending = butterfly-identical k-order
  if (lane < KNN){
    unsigned mk = skey[wv][lane]; int mi = sidx[wv][lane];
    int r = 0;
#pragma unroll
    for (int m=0;m<KNN;m++){
      unsigned ok = skey[wv][m]; int oi = sidx[wv][m];
      r += (ok < mk || (ok == mk && oi < mi)) ? 1 : 0;
    }
    knn[(size_t)(g*MM + i)*KNN + r] = g*MM + mi;
  }
}

// ------------------------------------------------------------ aggregation ---
// norm is constant 1/15 (every node is dst exactly 15 times -> deg==15).
__global__ void agg7_kernel(const float* __restrict__ src,
                            const int* __restrict__ knn,
                            float* __restrict__ out){
  int i = blockIdx.x*blockDim.x + threadIdx.x;
  if (i >= NN*FIN) return;
  int n = i / FIN, c = i - n*FIN;
  const int* kn = knn + (size_t)n*KNN;
  float s = 0.f;
#pragma unroll
  for (int k=0;k<KNN;k++) s += src[(size_t)kn[k]*FIN + c];
  out[i] = s * (1.f/15.f);
}

// bf16 h: 8 nodes/block, 16 lanes x 8 channels = 128 per node.
// XCD-locality swizzle: round-robin block->XCD dispatch; remap so XCD x
// covers contiguous graphs -> 2 MB/XCD working set fits 4 MB L2.
__global__ __launch_bounds__(128) void agg128_kernel(const unsigned short* __restrict__ src,
                                                     const int* __restrict__ knn,
                                                     unsigned short* __restrict__ out){
  const int tid = threadIdx.x;
  const int nb  = (blockIdx.x & 7) * 1024 + (blockIdx.x >> 3);  // 8192 blocks
  const int n   = nb*8 + (tid >> 4);
  const int c8  = (tid & 15) * 8;
  const int* kn = knn + (size_t)n*KNN;
  float s[8];
#pragma unroll
  for (int e=0;e<8;e++) s[e]=0.f;
#pragma unroll
  for (int k=0;k<KNN;k++){
    uint4 r = *(const uint4*)(src + (size_t)kn[k]*CC + c8);
    s[0] += __uint_as_float(r.x << 16); s[1] += __uint_as_float(r.x & 0xFFFF0000u);
    s[2] += __uint_as_float(r.y << 16); s[3] += __uint_as_float(r.y & 0xFFFF0000u);
    s[4] += __uint_as_float(r.z << 16); s[5] += __uint_as_float(r.z & 0xFFFF0000u);
    s[6] += __uint_as_float(r.w << 16); s[7] += __uint_as_float(r.w & 0xFFFF0000u);
  }
  const float inv = 1.f/15.f;
  uint4 o;
  o.x = (unsigned)f2bf(s[0]*inv) | ((unsigned)f2bf(s[1]*inv) << 16);
  o.y = (unsigned)f2bf(s[2]*inv) | ((unsigned)f2bf(s[3]*inv) << 16);
  o.z = (unsigned)f2bf(s[4]*inv) | ((unsigned)f2bf(s[5]*inv) << 16);
  o.w = (unsigned)f2bf(s[6]*inv) | ((unsigned)f2bf(s[7]*inv) << 16);
  *(uint4*)(out + (size_t)n*CC + c8) = o;
}

// ------------------------------------------------------------ conv layer 1 --
// 16 nodes/block, W column (21 floats) cached in registers -> 16x less W
// traffic than the old node-per-block version. Same FMA order (t ascending)
// -> bit-identical output.
__global__ __launch_bounds__(128) void conv1_kernel(const float* __restrict__ x,
                                                    const float* __restrict__ a1,
                                                    const float* __restrict__ a2,
                                                    const float* __restrict__ W,
                                                    const float* __restrict__ b,
                                                    unsigned short* __restrict__ out){
  __shared__ float feat[16][3*FIN];
  const int n0 = blockIdx.x*16;
  const int c  = threadIdx.x;
  for (int e=c; e<16*3*FIN; e+=128){
    int nn = e / (3*FIN), f = e - nn*(3*FIN);
    float v;
    if (f < FIN)        v = x [(size_t)(n0+nn)*FIN + f];
    else if (f < 2*FIN) v = a1[(size_t)(n0+nn)*FIN + (f-FIN)];
    else                v = a2[(size_t)(n0+nn)*FIN + (f-2*FIN)];
    feat[nn][f] = v;
  }
  __syncthreads();
  float wcol[3*FIN];
#pragma unroll
  for (int t2=0;t2<3*FIN;t2++) wcol[t2] = W[t2*CC + c];
  const float bc = b[c];
  for (int nn=0;nn<16;nn++){
    float acc = bc;
#pragma unroll
    for (int t2=0;t2<3*FIN;t2++) acc += feat[nn][t2]*wcol[t2];
    out[(size_t)(n0+nn)*CC + c] = f2bf(lrelu(acc));
  }
}

// ----------------------------------------------- pack W into B-frag order ---
__global__ void packW_kernel(const float* __restrict__ W2src,
                             const float* __restrict__ W3src,
                             unsigned short* __restrict__ W2dst,
                             unsigned short* __restrict__ W3dst){
  int idx = blockIdx.x*256 + threadIdx.x;   // [0, 2*3*128*128)
  if (idx >= 2*3*CC*CC) return;
  const float* Wsrc = (idx < 3*CC*CC) ? W2src : W3src;
  unsigned short* Wdst = (idx < 3*CC*CC) ? W2dst : W3dst;
  int e = (idx < 3*CC*CC) ? idx : idx - 3*CC*CC;
  int kg = e >> 7;             // hop*128 + k  (0..383)
  int n  = e & 127;
  int ck = kg >> 5, q = (kg >> 3) & 3, j = kg & 7;
  Wdst[(((ck*4 + q)*CC) + n)*8 + j] = f2bf(Wsrc[e]);
}

// -------------------------------------------- conv layers 2/3 (bf16 MFMA) ---
// 128x128 block tile, 4 waves of 64x64, mfma_f32_16x16x32_bf16, K=384.
// out must NOT alias p0/p1/p2 (no barrier before the epilogue writes).
__global__ __launch_bounds__(256) void conv_mfma_kernel(
    const unsigned short* __restrict__ p0,
    const unsigned short* __restrict__ p1,
    const unsigned short* __restrict__ p2,
    const unsigned short* __restrict__ Wpk,
    const float* __restrict__ bias,
    unsigned short* __restrict__ out){
  const int tid  = threadIdx.x;
  const int wv   = tid >> 6, lane = tid & 63;
  const int n    = lane & 15, q = lane >> 4;
  const int rows0 = blockIdx.x*128 + (wv & 1)*64;
  const int cols0 = (wv >> 1)*64;

  f32x4 acc[4][4];
#pragma unroll
  for (int i=0;i<4;i++)
#pragma unroll
    for (int t=0;t<4;t++) acc[i][t] = (f32x4){0.f,0.f,0.f,0.f};

#pragma unroll
  for (int ck=0; ck<12; ck++){
    const unsigned short* A = (ck < 4) ? p0 : (ck < 8) ? p1 : p2;
    const int kc = ck & 3;
    const unsigned short* ab = A + (size_t)(rows0 + n)*CC + kc*32 + q*8;
    bf16x8 af[4];
#pragma unroll
    for (int i=0;i<4;i++) af[i] = *(const bf16x8*)(ab + (size_t)i*16*CC);
    const unsigned short* wb = Wpk + ((size_t)(ck*4 + q)*CC + cols0 + n)*8;
    bf16x8 bf[4];
#pragma unroll
    for (int t=0;t<4;t++) bf[t] = *(const bf16x8*)(wb + t*16*8);
#pragma unroll
    for (int i=0;i<4;i++)
#pragma unroll
      for (int t=0;t<4;t++)
        acc[i][t] = __builtin_amdgcn_mfma_f32_16x16x32_bf16(af[i], bf[t], acc[i][t], 0, 0, 0);
  }

  float bv[4];
#pragma unroll
  for (int t=0;t<4;t++) bv[t] = bias[cols0 + t*16 + n];
#pragma unroll
  for (int i=0;i<4;i++){
#pragma unroll
    for (int t=0;t<4;t++){
#pragma unroll
      for (int r=0;r<4;r++){
        int row = rows0 + i*16 + q*4 + r;
        int col = cols0 + t*16 + n;
        out[(size_t)row*CC + col] = f2bf(lrelu(acc[i][t][r] + bv[t]));
      }
    }
  }
}

// ------------------------------------------------------------------ pooling -
__global__ __launch_bounds__(512) void pool_kernel(const unsigned short* __restrict__ h,
                                                   float* __restrict__ gf, int off){
  __shared__ float smean[4][CC];
  __shared__ float smax [4][CC];
  const int g = blockIdx.x, tid = threadIdx.x;
  const int c = tid & 127, grp = tid >> 7;
  const unsigned short* hp = h + (size_t)g*MM*CC + c;
  float s = 0.f, mx = -FINF;
  for (int m=grp*64; m<grp*64+64; m++){
    float v = bf2f(hp[(size_t)m*CC]);
    s += v; mx = fmaxf(mx, v);
  }
  smean[grp][c] = s; smax[grp][c] = mx;
  __syncthreads();
  if (grp == 0){
    s  = smean[0][c] + smean[1][c] + smean[2][c] + smean[3][c];
    mx = fmaxf(fmaxf(smax[0][c], smax[1][c]), fmaxf(smax[2][c], smax[3][c]));
    gf[(size_t)g*C2 + off + c]      = s * (1.f/MM);
    gf[(size_t)g*C2 + off + CC + c] = mx;
  }
}

// ---------------------------------------------------------------- batchnorm -
__global__ __launch_bounds__(256) void bn_kernel(float* __restrict__ g,
                                                 const float* __restrict__ gamma,
                                                 const float* __restrict__ beta){
  __shared__ float ssum[4][64], ssq[4][64], ssc[64], ssh[64];
  const int cl = threadIdx.x & 63, rg = threadIdx.x >> 6;
  const int c  = blockIdx.x*64 + cl;
  float s=0.f, q=0.f;
  for (int r=rg*64; r<rg*64+64; r++){
    float v = g[(size_t)r*C2 + c];
    s += v; q += v*v;
  }
  ssum[rg][cl]=s; ssq[rg][cl]=q;
  __syncthreads();
  if (rg == 0){
    s = ssum[0][cl]+ssum[1][cl]+ssum[2][cl]+ssum[3][cl];
    q = ssq [0][cl]+ssq [1][cl]+ssq [2][cl]+ssq [3][cl];
    float mu  = s * (1.f/NB);
    float var = q * (1.f/NB) - mu*mu;
    float sc  = rsqrtf(var + 1e-5f) * gamma[c];
    ssc[cl] = sc;
    ssh[cl] = beta[c] - mu*sc;
  }
  __syncthreads();
  const float sc = ssc[cl], sh = ssh[cl];
  for (int r=rg*64; r<rg*64+64; r++){
    size_t ix = (size_t)r*C2 + c;
    g[ix] = g[ix]*sc + sh;
  }
}

// -------------------------------------------------------------- MLP (GEMM) --
__global__ __launch_bounds__(256) void mlp_gemm_kernel(const float* __restrict__ A,
                                                       const float* __restrict__ W,
                                                       const float* __restrict__ b,
                                                       float* __restrict__ out){
  __shared__ float Ast[32][16];
  __shared__ float Ws [32][128];
  const int tid = threadIdx.x;
  const int row0 = blockIdx.y * 16;
  const int col0 = blockIdx.x * 128;
  const int tr = tid >> 5, tc = tid & 31;
  float acc[2][4] = {{0.f,0.f,0.f,0.f},{0.f,0.f,0.f,0.f}};
  for (int kt=0; kt<24; kt++){
    __syncthreads();
    if (tid < 128){
      int r   = tid >> 3;
      int kc4 = (tid & 7)*4;
      float4 v = *(const float4*)(A + (size_t)(row0+r)*C2 + kt*32 + kc4);
      Ast[kc4+0][r]=v.x; Ast[kc4+1][r]=v.y; Ast[kc4+2][r]=v.z; Ast[kc4+3][r]=v.w;
    }
#pragma unroll
    for (int q=0;q<4;q++){
      int chunk = tid + q*256;
      int kr = chunk >> 5;
      int c4 = (chunk & 31)*4;
      *(float4*)(&Ws[kr][c4]) = *(const float4*)(W + (size_t)(kt*32+kr)*C2 + col0 + c4);
    }
    __syncthreads();
#pragma unroll 8
    for (int kk=0;kk<32;kk++){
      float4 w = *(const float4*)(&Ws[kk][tc*4]);
      float a0 = Ast[kk][tr*2+0];
      float a1 = Ast[kk][tr*2+1];
      acc[0][0] += a0*w.x; acc[0][1] += a0*w.y; acc[0][2] += a0*w.z; acc[0][3] += a0*w.w;
      acc[1][0] += a1*w.x; acc[1][1] += a1*w.y; acc[1][2] += a1*w.z; acc[1][3] += a1*w.w;
    }
  }
  const int c0 = col0 + tc*4;
  float4 bv = *(const float4*)(b + c0);
#pragma unroll
  for (int i=0;i<2;i++){
    int r = row0 + tr*2 + i;
    float4 o;
    o.x = lrelu(acc[i][0]+bv.x);
    o.y = lrelu(acc[i][1]+bv.y);
    o.z = lrelu(acc[i][2]+bv.z);
    o.w = lrelu(acc[i][3]+bv.w);
    *(float4*)(out + (size_t)r*C2 + c0) = o;
  }
}

// ------------------------------------------------------------- final layer --
__global__ __launch_bounds__(256) void final_kernel(const float* __restrict__ g,
                                                    const float* __restrict__ Wo,
                                                    const float* __restrict__ bo,
                                                    float* __restrict__ out){
  int i = blockIdx.x*256 + threadIdx.x;   // 0..767
  if (i >= NB*NL) return;
  int r = i / NL, c = i - r*NL;
  const float* gr = g + (size_t)r*C2;
  float acc = bo[c];
  for (int k=0;k<C2;k++) acc += gr[k]*Wo[k*NL + c];
  if (c < 2) acc = tanhf(acc);
  out[i] = acc;
}

// ------------------------------------------------------------------ launch --
extern "C" void kernel_launch(void* const* d_in, const int* in_sizes, int n_in,
                              void* d_out, int out_size, void* d_ws, size_t ws_size,
                              hipStream_t stream){
  const float* x   = (const float*)d_in[0];
  const float* Wc1 = (const float*)d_in[1];
  const float* bc1 = (const float*)d_in[2];
  const float* Wc2 = (const float*)d_in[3];
  const float* bc2 = (const float*)d_in[4];
  const float* Wc3 = (const float*)d_in[5];
  const float* bc3 = (const float*)d_in[6];
  const float* bng = (const float*)d_in[7];
  const float* bnb = (const float*)d_in[8];
  const float* W1  = (const float*)d_in[9];
  const float* b1  = (const float*)d_in[10];
  const float* W2  = (const float*)d_in[11];
  const float* b2  = (const float*)d_in[12];
  const float* W3  = (const float*)d_in[13];
  const float* b3  = (const float*)d_in[14];
  const float* W4  = (const float*)d_in[15];
  const float* b4  = (const float*)d_in[16];
  const float* W5  = (const float*)d_in[17];
  const float* b5  = (const float*)d_in[18];
  const float* Wo  = (const float*)d_in[19];
  const float* bo  = (const float*)d_in[20];

  char* ws = (char*)d_ws;
  size_t o = 0;
  int*            knn  = (int*)           (ws + o); o += (size_t)NN*KNN*4;   // 3.93 MB
  unsigned short* h0   = (unsigned short*)(ws + o); o += (size_t)NN*CC*2;    // 16.8 MB
  unsigned short* h1   = (unsigned short*)(ws + o); o += (size_t)NN*CC*2;
  unsigned short* h2   = (unsigned short*)(ws + o); o += (size_t)NN*CC*2;
  unsigned short* h3   = (unsigned short*)(ws + o); o += (size_t)NN*CC*2;
  float*          ax1  = (float*)         (ws + o); o += (size_t)NN*FIN*4;   // 1.84 MB
  float*          ax2  = (float*)         (ws + o); o += (size_t)NN*FIN*4;
  float*          gf   = (float*)         (ws + o); o += (size_t)NB*C2*4;
  float*          gt   = (float*)         (ws + o); o += (size_t)NB*C2*4;
  unsigned short* Wpk2 = (unsigned short*)(ws + o); o += (size_t)3*CC*CC*2;
  unsigned short* Wpk3 = (unsigned short*)(ws + o); o += (size_t)3*CC*CC*2;

  knn_kernel<<<NB*64, 256, 0, stream>>>(x, knn);
  packW_kernel<<<384, 256, 0, stream>>>(Wc2, Wc3, Wpk2, Wpk3);

  const int tot7 = NN*FIN;
  agg7_kernel<<<(tot7+255)/256, 256, 0, stream>>>(x,   knn, ax1);
  agg7_kernel<<<(tot7+255)/256, 256, 0, stream>>>(ax1, knn, ax2);
  conv1_kernel<<<NN/16, 128, 0, stream>>>(x, ax1, ax2, Wc1, bc1, h0);
  pool_kernel<<<NB, 512, 0, stream>>>(h0, gf, 0);

  // layer 2: reads h0 -> writes h3 (no aliasing with inputs h0/h1/h2)
  agg128_kernel<<<NN/8, 128, 0, stream>>>(h0, knn, h1);
  agg128_kernel<<<NN/8, 128, 0, stream>>>(h1, knn, h2);
  conv_mfma_kernel<<<NN/128, 256, 0, stream>>>(h0, h1, h2, Wpk2, bc2, h3);
  pool_kernel<<<NB, 512, 0, stream>>>(h3, gf, 2*CC);

  // layer 3: reads h3 -> writes h0 (h0's layer-1 contents no longer needed)
  agg128_kernel<<<NN/8, 128, 0, stream>>>(h3, knn, h1);
  agg128_kernel<<<NN/8, 128, 0, stream>>>(h1, knn, h2);
  conv_mfma_kernel<<<NN/128, 256, 0, stream>>>(h3, h1, h2, Wpk3, bc3, h0);
  pool_kernel<<<NB, 512, 0, stream>>>(h0, gf, 4*CC);

  bn_kernel<<<12, 256, 0, stream>>>(gf, bng, bnb);

  dim3 mgrid(6, 16);
  mlp_gemm_kernel<<<mgrid, 256, 0, stream>>>(gf, W1, b1, gt);
  mlp_gemm_kernel<<<mgrid, 256, 0, stream>>>(gt, W2, b2, gf);
  mlp_gemm_kernel<<<mgrid, 256, 0, stream>>>(gf, W3, b3, gt);
  mlp_gemm_kernel<<<mgrid, 256, 0, stream>>>(gt, W4, b4, gf);
  mlp_gemm_kernel<<<mgrid, 256, 0, stream>>>(gf, W5, b5, gt);

  final_kernel<<<3, 256, 0, stream>>>(gt, Wo, bo, (float*)d_out);
}

// Round 10
// 465.143 us; speedup vs baseline: 2.2540x; 1.2585x over previous
//
#include <hip/hip_runtime.h>
#include <cstdint>
#include <cmath>

#define NB 256      // graphs (B)
#define MM 256      // nodes per graph
#define NN (NB*MM)  // 65536 nodes
#define KNN 15
#define FIN 7
#define CC 128
#define CCP 136     // padded LDS row stride (shorts): 272B = 68 dwords, 68%32=4
                    // -> MFMA A-frag lane rows hit banks 4n%32 = 2-way (free)
#define C2 768
#define NL 3
#define FINF 3.4e38f

__device__ __forceinline__ float lrelu(float v){ return v > 0.f ? v : 0.01f*v; }

// bf16 helpers (RNE round; storage = unsigned short)
__device__ __forceinline__ unsigned short f2bf(float f){
  unsigned u = __float_as_uint(f);
  return (unsigned short)((u + 0x7FFFu + ((u >> 16) & 1u)) >> 16);
}
__device__ __forceinline__ float bf2f(unsigned short h){
  return __uint_as_float(((unsigned)h) << 16);
}

__device__ __forceinline__ int mbcnt64(unsigned long long m){
  return (int)__builtin_amdgcn_mbcnt_hi((unsigned)(m >> 32),
              __builtin_amdgcn_mbcnt_lo((unsigned)m, 0u));
}

typedef short bf16x8 __attribute__((ext_vector_type(8)));
typedef float f32x4  __attribute__((ext_vector_type(4)));

// ---------------------------------------------------------------- kNN -------
// Radix-select (R9 WIN: 143 -> 58 us). __ballot + popcount binary search for
// the 15th-smallest sortable-u32 key; exact (key,idx) rank-sort through LDS
// emits butterfly-identical k-order (aggregation sum order preserved).
__global__ __launch_bounds__(256) void knn_kernel(const float* __restrict__ x,
                                                  int* __restrict__ knn){
  __shared__ float4 pos[MM];
  __shared__ float  sq[MM];
  __shared__ unsigned skey[4][16];
  __shared__ int      sidx[4][16];
  const int g = blockIdx.x >> 6;               // 64 blocks per graph
  const int t = threadIdx.x;
  const float* xr = x + (size_t)(g*MM + t)*FIN;
  float4 p = make_float4(xr[0], xr[1], xr[2], xr[3]);
  pos[t] = p;
  sq[t]  = p.x*p.x + p.y*p.y + p.z*p.z + p.w*p.w;
  __syncthreads();

  const int i    = (blockIdx.x & 63)*4 + (t >> 6);  // wave's node
  const int wv   = t >> 6;
  const int lane = t & 63;
  const float4 pi = pos[i];
  const float  sqi = sq[i];

  unsigned key[4];
#pragma unroll
  for (int q=0;q<4;q++){
    int j = q*64 + lane;
    float4 pj = pos[j];
    float dot = pi.x*pj.x + pi.y*pj.y + pi.z*pj.z + pi.w*pj.w;
    float d2  = sqi + sq[j] - 2.f*dot;          // exact reference arithmetic
    unsigned u = __float_as_uint(d2);
    u = ((int)u < 0) ? ~u : (u ^ 0x80000000u);  // monotone f32 -> u32
    key[q] = (j == i) ? 0xFFFFFFFFu : u;        // self-exclusion sentinel
  }

  unsigned prefix = 0u;
#pragma unroll
  for (int bit=31; bit>=0; --bit){
    unsigned trial = prefix | (1u << bit);
    int c = __popcll(__ballot(key[0] < trial))
          + __popcll(__ballot(key[1] < trial))
          + __popcll(__ballot(key[2] < trial))
          + __popcll(__ballot(key[3] < trial));
    if (c < KNN) prefix = trial;
  }
  const unsigned K = prefix;

  int c_lt = __popcll(__ballot(key[0] < K)) + __popcll(__ballot(key[1] < K))
           + __popcll(__ballot(key[2] < K)) + __popcll(__ballot(key[3] < K));
  int need = KNN - c_lt;
  bool w[4];
  int eqbase = 0;
#pragma unroll
  for (int q=0;q<4;q++){
    unsigned long long em = __ballot(key[q] == K);
    int gr = eqbase + mbcnt64(em);
    w[q] = (key[q] < K) || ((key[q] == K) && (gr < need));
    eqbase += __popcll(em);
  }

  int base = 0;
#pragma unroll
  for (int q=0;q<4;q++){
    unsigned long long wm = __ballot(w[q]);
    int rk = mbcnt64(wm);
    if (w[q]){ skey[wv][base+rk] = key[q]; sidx[wv][base+rk] = q*64 + lane; }
    base += __popcll(wm);
  }
  __builtin_amdgcn_wave_barrier();

  if (lane < KNN){
    unsigned mk = skey[wv][lane]; int mi = sidx[wv][lane];
    int r = 0;
#pragma unroll
    for (int m=0;m<KNN;m++){
      unsigned ok = skey[wv][m]; int oi = sidx[wv][m];
      r += (ok < mk || (ok == mk && oi < mi)) ? 1 : 0;
    }
    knn[(size_t)(g*MM + i)*KNN + r] = g*MM + mi;
  }
}

// ------------------------------------- layer 1 fused (agg7 x2 + conv1) -----
// One block per graph; x / a1 / a2 live in LDS (21 KB). Arithmetic order per
// (n,c) identical to the split agg7/conv1 kernels -> bit-identical h0.
__global__ __launch_bounds__(256) void layer1_fused_kernel(
    const float* __restrict__ x, const int* __restrict__ knn,
    const float* __restrict__ W, const float* __restrict__ b,
    unsigned short* __restrict__ out){
  __shared__ float xg[MM*FIN];
  __shared__ float a1[MM*FIN];
  __shared__ float a2[MM*FIN];
  const int g = blockIdx.x, tid = threadIdx.x;
  for (int e=tid; e<MM*FIN; e+=256) xg[e] = x[(size_t)g*MM*FIN + e];
  __syncthreads();
  {
    const int nn = tid;
    const int* kn = knn + (size_t)(g*MM + nn)*KNN;
    int loc[KNN];
#pragma unroll
    for (int k=0;k<KNN;k++) loc[k] = kn[k] & (MM-1);
#pragma unroll
    for (int c=0;c<FIN;c++){
      float s = 0.f;
#pragma unroll
      for (int k=0;k<KNN;k++) s += xg[loc[k]*FIN + c];
      a1[nn*FIN + c] = s * (1.f/15.f);
    }
    __syncthreads();
#pragma unroll
    for (int c=0;c<FIN;c++){
      float s = 0.f;
#pragma unroll
      for (int k=0;k<KNN;k++) s += a1[loc[k]*FIN + c];
      a2[nn*FIN + c] = s * (1.f/15.f);
    }
  }
  __syncthreads();
  // conv1: threads 0-127 -> rows 0-127, threads 128-255 -> rows 128-255
  const int c    = tid & 127;
  const int half = tid >> 7;
  float wcol[3*FIN];
#pragma unroll
  for (int t2=0;t2<3*FIN;t2++) wcol[t2] = W[t2*CC + c];
  const float bc = b[c];
  for (int nn=half*128; nn<half*128+128; ++nn){
    float acc = bc;
#pragma unroll
    for (int t2=0;t2<FIN;t2++) acc += xg[nn*FIN + t2] * wcol[t2];
#pragma unroll
    for (int t2=0;t2<FIN;t2++) acc += a1[nn*FIN + t2] * wcol[FIN + t2];
#pragma unroll
    for (int t2=0;t2<FIN;t2++) acc += a2[nn*FIN + t2] * wcol[2*FIN + t2];
    out[(size_t)(g*MM + nn)*CC + c] = f2bf(lrelu(acc));
  }
}

// ----------------------------------------------- pack W into B-frag order ---
__global__ void packW_kernel(const float* __restrict__ W2src,
                             const float* __restrict__ W3src,
                             unsigned short* __restrict__ W2dst,
                             unsigned short* __restrict__ W3dst){
  int idx = blockIdx.x*256 + threadIdx.x;   // [0, 2*3*128*128)
  if (idx >= 2*3*CC*CC) return;
  const float* Wsrc = (idx < 3*CC*CC) ? W2src : W3src;
  unsigned short* Wdst = (idx < 3*CC*CC) ? W2dst : W3dst;
  int e = (idx < 3*CC*CC) ? idx : idx - 3*CC*CC;
  int kg = e >> 7;             // hop*128 + k  (0..383)
  int n  = e & 127;
  int ck = kg >> 5, q = (kg >> 3) & 3, j = kg & 7;
  Wdst[(((ck*4 + q)*CC) + n)*8 + j] = f2bf(Wsrc[e]);
}

// ---------------------- exact agg128 arithmetic, LDS->LDS, padded stride ----
__device__ __forceinline__ void agg_lds(const unsigned short* __restrict__ src,
                                        unsigned short* __restrict__ dst,
                                        const int* __restrict__ kn_graph,
                                        int tid){
  for (int it=0; it<8; ++it){
    int idx = it*512 + tid;                 // 4096 (node, c8) items
    int nn  = idx >> 4;
    int c8  = (idx & 15) * 8;
    const int* kn = kn_graph + nn*KNN;
    float s[8];
#pragma unroll
    for (int e=0;e<8;e++) s[e]=0.f;
#pragma unroll
    for (int k=0;k<KNN;k++){
      int loc = kn[k] & (MM-1);
      uint4 r = *(const uint4*)(src + loc*CCP + c8);
      s[0] += __uint_as_float(r.x << 16); s[1] += __uint_as_float(r.x & 0xFFFF0000u);
      s[2] += __uint_as_float(r.y << 16); s[3] += __uint_as_float(r.y & 0xFFFF0000u);
      s[4] += __uint_as_float(r.z << 16); s[5] += __uint_as_float(r.z & 0xFFFF0000u);
      s[6] += __uint_as_float(r.w << 16); s[7] += __uint_as_float(r.w & 0xFFFF0000u);
    }
    const float inv = 1.f/15.f;
    uint4 o;
    o.x = (unsigned)f2bf(s[0]*inv) | ((unsigned)f2bf(s[1]*inv) << 16);
    o.y = (unsigned)f2bf(s[2]*inv) | ((unsigned)f2bf(s[3]*inv) << 16);
    o.z = (unsigned)f2bf(s[4]*inv) | ((unsigned)f2bf(s[5]*inv) << 16);
    o.w = (unsigned)f2bf(s[6]*inv) | ((unsigned)f2bf(s[7]*inv) << 16);
    *(uint4*)(dst + nn*CCP + c8) = o;
  }
}

// ------------------------- conv layer 2/3 fully fused (agg+agg+MFMA) -------
// One block per graph, 512 threads (8 waves: 4 row x 2 col 64x64 tiles).
// bufh: h, later overwritten by a2. bufa: a1. 2 x 68 KB LDS (row pad CCP).
// MFMA accumulation order ck0..11 identical to the split conv_mfma kernel;
// agg arithmetic identical to agg128 -> bit-identical output.
__global__ __launch_bounds__(512) void conv_fused_kernel(
    const unsigned short* __restrict__ hin,
    const int* __restrict__ knn,
    const unsigned short* __restrict__ Wpk,
    const float* __restrict__ bias,
    unsigned short* __restrict__ hout){
  __shared__ unsigned short bufh[MM*CCP];   // 69632 B
  __shared__ unsigned short bufa[MM*CCP];   // 69632 B
  const int g   = blockIdx.x;
  const int tid = threadIdx.x;
  const int* kn_graph = knn + (size_t)g*MM*KNN;

  // stage h -> bufh (row-padded)
  {
    const uint4* src = (const uint4*)(hin + (size_t)g*MM*CC);
    for (int e=tid; e<MM*CC/8; e+=512){
      int row = e >> 4, ch = e & 15;                 // 16 uint4 per 256B row
      *(uint4*)(bufh + row*CCP + ch*8) = src[e];
    }
  }
  __syncthreads();

  // a1 = agg(h)
  agg_lds(bufh, bufa, kn_graph, tid);
  __syncthreads();

  const int wv   = tid >> 6, lane = tid & 63;
  const int n    = lane & 15, q = lane >> 4;
  const int rows0 = (wv & 3)*64;
  const int cols0 = (wv >> 2)*64;

  f32x4 acc[4][4];
#pragma unroll
  for (int i=0;i<4;i++)
#pragma unroll
    for (int t=0;t<4;t++) acc[i][t] = (f32x4){0.f,0.f,0.f,0.f};

  // MFMA ck 0..7: h from bufh (ck0-3), a1 from bufa (ck4-7)
#pragma unroll
  for (int ck=0; ck<8; ck++){
    const unsigned short* A = (ck < 4) ? bufh : bufa;
    const int kc = ck & 3;
    const unsigned short* ab = A + (rows0 + n)*CCP + kc*32 + q*8;
    bf16x8 af[4];
#pragma unroll
    for (int i=0;i<4;i++) af[i] = *(const bf16x8*)(ab + i*16*CCP);
    const unsigned short* wb = Wpk + ((size_t)(ck*4 + q)*CC + cols0 + n)*8;
    bf16x8 bf[4];
#pragma unroll
    for (int t=0;t<4;t++) bf[t] = *(const bf16x8*)(wb + t*16*8);
#pragma unroll
    for (int i=0;i<4;i++)
#pragma unroll
      for (int t=0;t<4;t++)
        acc[i][t] = __builtin_amdgcn_mfma_f32_16x16x32_bf16(af[i], bf[t], acc[i][t], 0, 0, 0);
  }
  __syncthreads();                 // all ck0-3 reads of bufh retired

  // a2 = agg(a1) -> overwrite bufh
  agg_lds(bufa, bufh, kn_graph, tid);
  __syncthreads();

  // MFMA ck 8..11: a2 from bufh
#pragma unroll
  for (int ck=8; ck<12; ck++){
    const int kc = ck & 3;
    const unsigned short* ab = bufh + (rows0 + n)*CCP + kc*32 + q*8;
    bf16x8 af[4];
#pragma unroll
    for (int i=0;i<4;i++) af[i] = *(const bf16x8*)(ab + i*16*CCP);
    const unsigned short* wb = Wpk + ((size_t)(ck*4 + q)*CC + cols0 + n)*8;
    bf16x8 bf[4];
#pragma unroll
    for (int t=0;t<4;t++) bf[t] = *(const bf16x8*)(wb + t*16*8);
#pragma unroll
    for (int i=0;i<4;i++)
#pragma unroll
      for (int t=0;t<4;t++)
        acc[i][t] = __builtin_amdgcn_mfma_f32_16x16x32_bf16(af[i], bf[t], acc[i][t], 0, 0, 0);
  }

  float bv[4];
#pragma unroll
  for (int t=0;t<4;t++) bv[t] = bias[cols0 + t*16 + n];
#pragma unroll
  for (int i=0;i<4;i++){
#pragma unroll
    for (int t=0;t<4;t++){
#pragma unroll
      for (int r=0;r<4;r++){
        int row = g*MM + rows0 + i*16 + q*4 + r;
        int col = cols0 + t*16 + n;
        hout[(size_t)row*CC + col] = f2bf(lrelu(acc[i][t][r] + bv[t]));
      }
    }
  }
}

// ------------------------------------------------------------------ pooling -
__global__ __launch_bounds__(512) void pool_kernel(const unsigned short* __restrict__ h,
                                                   float* __restrict__ gf, int off){
  __shared__ float smean[4][CC];
  __shared__ float smax [4][CC];
  const int g = blockIdx.x, tid = threadIdx.x;
  const int c = tid & 127, grp = tid >> 7;
  const unsigned short* hp = h + (size_t)g*MM*CC + c;
  float s = 0.f, mx = -FINF;
  for (int m=grp*64; m<grp*64+64; m++){
    float v = bf2f(hp[(size_t)m*CC]);
    s += v; mx = fmaxf(mx, v);
  }
  smean[grp][c] = s; smax[grp][c] = mx;
  __syncthreads();
  if (grp == 0){
    s  = smean[0][c] + smean[1][c] + smean[2][c] + smean[3][c];
    mx = fmaxf(fmaxf(smax[0][c], smax[1][c]), fmaxf(smax[2][c], smax[3][c]));
    gf[(size_t)g*C2 + off + c]      = s * (1.f/MM);
    gf[(size_t)g*C2 + off + CC + c] = mx;
  }
}

// ---------------------------------------------------------------- batchnorm -
__global__ __launch_bounds__(256) void bn_kernel(float* __restrict__ g,
                                                 const float* __restrict__ gamma,
                                                 const float* __restrict__ beta){
  __shared__ float ssum[4][64], ssq[4][64], ssc[64], ssh[64];
  const int cl = threadIdx.x & 63, rg = threadIdx.x >> 6;
  const int c  = blockIdx.x*64 + cl;
  float s=0.f, q=0.f;
  for (int r=rg*64; r<rg*64+64; r++){
    float v = g[(size_t)r*C2 + c];
    s += v; q += v*v;
  }
  ssum[rg][cl]=s; ssq[rg][cl]=q;
  __syncthreads();
  if (rg == 0){
    s = ssum[0][cl]+ssum[1][cl]+ssum[2][cl]+ssum[3][cl];
    q = ssq [0][cl]+ssq [1][cl]+ssq [2][cl]+ssq [3][cl];
    float mu  = s * (1.f/NB);
    float var = q * (1.f/NB) - mu*mu;
    float sc  = rsqrtf(var + 1e-5f) * gamma[c];
    ssc[cl] = sc;
    ssh[cl] = beta[c] - mu*sc;
  }
  __syncthreads();
  const float sc = ssc[cl], sh = ssh[cl];
  for (int r=rg*64; r<rg*64+64; r++){
    size_t ix = (size_t)r*C2 + c;
    g[ix] = g[ix]*sc + sh;
  }
}

// -------------------------------------------------------------- MLP (GEMM) --
// 8 rows x 128 cols per block, grid (6,32) = 192 blocks (75% CU coverage vs
// 96 blocks before). Per-output k-order (kt asc, kk asc) unchanged -> bit-
// identical results.
__global__ __launch_bounds__(256) void mlp_gemm_kernel(const float* __restrict__ A,
                                                       const float* __restrict__ W,
                                                       const float* __restrict__ b,
                                                       float* __restrict__ out){
  __shared__ float Ast[32][8];
  __shared__ float Ws [32][128];
  const int tid = threadIdx.x;
  const int row0 = blockIdx.y * 8;
  const int col0 = blockIdx.x * 128;
  const int tr = tid >> 5, tc = tid & 31;
  float acc[4] = {0.f,0.f,0.f,0.f};
  for (int kt=0; kt<24; kt++){
    __syncthreads();
    if (tid < 64){
      int r   = tid >> 3;
      int kc4 = (tid & 7)*4;
      float4 v = *(const float4*)(A + (size_t)(row0+r)*C2 + kt*32 + kc4);
      Ast[kc4+0][r]=v.x; Ast[kc4+1][r]=v.y; Ast[kc4+2][r]=v.z; Ast[kc4+3][r]=v.w;
    }
#pragma unroll
    for (int q=0;q<4;q++){
      int chunk = tid + q*256;
      int kr = chunk >> 5;
      int c4 = (chunk & 31)*4;
      *(float4*)(&Ws[kr][c4]) = *(const float4*)(W + (size_t)(kt*32+kr)*C2 + col0 + c4);
    }
    __syncthreads();
#pragma unroll 8
    for (int kk=0;kk<32;kk++){
      float4 w = *(const float4*)(&Ws[kk][tc*4]);
      float a0 = Ast[kk][tr];
      acc[0] += a0*w.x; acc[1] += a0*w.y; acc[2] += a0*w.z; acc[3] += a0*w.w;
    }
  }
  const int c0 = col0 + tc*4;
  float4 bv = *(const float4*)(b + c0);
  float4 o;
  o.x = lrelu(acc[0]+bv.x);
  o.y = lrelu(acc[1]+bv.y);
  o.z = lrelu(acc[2]+bv.z);
  o.w = lrelu(acc[3]+bv.w);
  *(float4*)(out + (size_t)(row0+tr)*C2 + c0) = o;
}

// ------------------------------------------------------------- final layer --
__global__ __launch_bounds__(256) void final_kernel(const float* __restrict__ g,
                                                    const float* __restrict__ Wo,
                                                    const float* __restrict__ bo,
                                                    float* __restrict__ out){
  int i = blockIdx.x*256 + threadIdx.x;   // 0..767
  if (i >= NB*NL) return;
  int r = i / NL, c = i - r*NL;
  const float* gr = g + (size_t)r*C2;
  float acc = bo[c];
  for (int k=0;k<C2;k++) acc += gr[k]*Wo[k*NL + c];
  if (c < 2) acc = tanhf(acc);
  out[i] = acc;
}

// ------------------------------------------------------------------ launch --
extern "C" void kernel_launch(void* const* d_in, const int* in_sizes, int n_in,
                              void* d_out, int out_size, void* d_ws, size_t ws_size,
                              hipStream_t stream){
  const float* x   = (const float*)d_in[0];
  const float* Wc1 = (const float*)d_in[1];
  const float* bc1 = (const float*)d_in[2];
  const float* Wc2 = (const float*)d_in[3];
  const float* bc2 = (const float*)d_in[4];
  const float* Wc3 = (const float*)d_in[5];
  const float* bc3 = (const float*)d_in[6];
  const float* bng = (const float*)d_in[7];
  const float* bnb = (const float*)d_in[8];
  const float* W1  = (const float*)d_in[9];
  const float* b1  = (const float*)d_in[10];
  const float* W2  = (const float*)d_in[11];
  const float* b2  = (const float*)d_in[12];
  const float* W3  = (const float*)d_in[13];
  const float* b3  = (const float*)d_in[14];
  const float* W4  = (const float*)d_in[15];
  const float* b4  = (const float*)d_in[16];
  const float* W5  = (const float*)d_in[17];
  const float* b5  = (const float*)d_in[18];
  const float* Wo  = (const float*)d_in[19];
  const float* bo  = (const float*)d_in[20];

  char* ws = (char*)d_ws;
  size_t o = 0;
  int*            knn  = (int*)           (ws + o); o += (size_t)NN*KNN*4;   // 3.93 MB
  unsigned short* h0   = (unsigned short*)(ws + o); o += (size_t)NN*CC*2;    // 16.8 MB
  unsigned short* h3   = (unsigned short*)(ws + o); o += (size_t)NN*CC*2;    // 16.8 MB
  float*          gf   = (float*)         (ws + o); o += (size_t)NB*C2*4;
  float*          gt   = (float*)         (ws + o); o += (size_t)NB*C2*4;
  unsigned short* Wpk2 = (unsigned short*)(ws + o); o += (size_t)3*CC*CC*2;
  unsigned short* Wpk3 = (unsigned short*)(ws + o); o += (size_t)3*CC*CC*2;

  knn_kernel<<<NB*64, 256, 0, stream>>>(x, knn);
  packW_kernel<<<384, 256, 0, stream>>>(Wc2, Wc3, Wpk2, Wpk3);

  layer1_fused_kernel<<<NB, 256, 0, stream>>>(x, knn, Wc1, bc1, h0);
  pool_kernel<<<NB, 512, 0, stream>>>(h0, gf, 0);

  conv_fused_kernel<<<NB, 512, 0, stream>>>(h0, knn, Wpk2, bc2, h3);
  pool_kernel<<<NB, 512, 0, stream>>>(h3, gf, 2*CC);

  conv_fused_kernel<<<NB, 512, 0, stream>>>(h3, knn, Wpk3, bc3, h0);
  pool_kernel<<<NB, 512, 0, stream>>>(h0, gf, 4*CC);

  bn_kernel<<<12, 256, 0, stream>>>(gf, bng, bnb);

  dim3 mgrid(6, 32);
  mlp_gemm_kernel<<<mgrid, 256, 0, stream>>>(gf, W1, b1, gt);
  mlp_gemm_kernel<<<mgrid, 256, 0, stream>>>(gt, W2, b2, gf);
  mlp_gemm_kernel<<<mgrid, 256, 0, stream>>>(gf, W3, b3, gt);
  mlp_gemm_kernel<<<mgrid, 256, 0, stream>>>(gt, W4, b4, gf);
  mlp_gemm_kernel<<<mgrid, 256, 0, stream>>>(gf, W5, b5, gt);

  final_kernel<<<3, 256, 0, stream>>>(gt, Wo, bo, (float*)d_out);
}